// Round 5
// baseline (439.045 us; speedup 1.0000x reference)
//
#include <hip/hip_runtime.h>
#include <hip/hip_bf16.h>
#include <math.h>

// Problem constants (fixed by setup_inputs)
#define BB 8
#define HH 56
#define WW 56
#define NN (HH*WW)          // 3136
#define CC 256
#define NH 8
#define NT (BB*NN)          // 25088
#define HID 128
#define MH 1024
#define SCALE 0.17677669529663687f   // 32^-0.5

typedef __attribute__((ext_vector_type(8))) short bf16x8;
typedef __attribute__((ext_vector_type(4))) float f32x4;

__device__ __forceinline__ ushort f2bf(float f) {
    __hip_bfloat16 h = __float2bfloat16(f);
    return *(ushort*)&h;
}
__device__ __forceinline__ uint pk2(float lo, float hi) {
    return ((uint)f2bf(hi) << 16) | (uint)f2bf(lo);
}
__device__ __forceinline__ float unlo(uint u) { return __uint_as_float(u << 16); }
__device__ __forceinline__ float unhi(uint u) { return __uint_as_float(u & 0xFFFF0000u); }

__device__ __forceinline__ void gload16(const void* g, void* s) {
    __builtin_amdgcn_global_load_lds(
        (const __attribute__((address_space(1))) void*)g,
        (__attribute__((address_space(3))) void*)s, 16, 0, 0);
}

// ---------------- weight transpose + f32->bf16: w[K][N] -> wt[N][K] --------
// 32x32 LDS tile transpose, coalesced both sides.
__global__ __launch_bounds__(256) void wtrans_kernel(
    const float* __restrict__ w, ushort* __restrict__ wt, int K, int N)
{
    __shared__ float tile[32][33];
    const int t = threadIdx.x;
    const int col = t & 31, rw = t >> 5;
    const int k0 = blockIdx.y * 32, n0 = blockIdx.x * 32;
    #pragma unroll
    for (int i = rw; i < 32; i += 8)
        tile[i][col] = w[(size_t)(k0 + i) * N + n0 + col];
    __syncthreads();
    #pragma unroll
    for (int i = rw; i < 32; i += 8)
        wt[(size_t)(n0 + i) * K + k0 + col] = f2bf(tile[col][i]);
}

// ---------------- CPE: depthwise 3x3 + bias + residual (sliding window) ----
__global__ __launch_bounds__(256) void cpe_kernel(
    const float* __restrict__ x, const float* __restrict__ w,
    const float* __restrict__ bias, float* __restrict__ out)
{
    __shared__ uint vt[4 * 34 * 32];
    const int qq = blockIdx.x >> 1, hx = blockIdx.x & 1;
    const int y0 = blockIdx.y * 2, b = blockIdx.z;
    const int x0 = hx * 28;
    const int t = threadIdx.x;
    const int c0 = qq * 64;

    // stage 4 rows x 34 cols x 64 ch (pairs 2p,2p+1), zero-padded
    {
        const int cw = t & 15, cg = t >> 4;
        for (int pos = cw; pos < 4 * 34; pos += 16) {
            int row = pos / 34, col = pos - row * 34;
            int gy = y0 + row - 1, gx = x0 + col - 3;
            float4 v = {0.f, 0.f, 0.f, 0.f};
            if ((unsigned)gy < 56u && (unsigned)gx < 56u)
                v = *(const float4*)(x + ((size_t)b * NN + gy * 56 + gx) * CC + c0 + cg * 4);
            uint2 pk = { pk2(v.x, v.y), pk2(v.z, v.w) };
            *(uint2*)&vt[pos * 32 + cg * 2] = pk;
        }
    }
    const int p = t & 31, rseg = t >> 5;
    const int r = rseg >> 2, sg = rseg & 3;
    const int cA = c0 + 2 * p;
    uint wpk[9];
    {
        const float* wA = w + cA * 9;
        const float* wB = wA + 9;
        #pragma unroll
        for (int i = 0; i < 9; ++i) wpk[i] = pk2(wA[i], wB[i]);
    }
    const float cbA = bias[cA], cbB = bias[cA + 1];
    __syncthreads();

    float accA[7], accB[7];
    #pragma unroll
    for (int k = 0; k < 7; ++k) { accA[k] = cbA; accB[k] = cbB; }

    #pragma unroll
    for (int dy = 0; dy < 3; ++dy) {
        const int rowbase = (r + dy) * 34 * 32;
        float fA[9], fB[9];
        #pragma unroll
        for (int u = 0; u < 9; ++u) {
            uint vv = vt[rowbase + (sg * 7 + 2 + u) * 32 + p];
            fA[u] = unlo(vv); fB[u] = unhi(vv);
        }
        #pragma unroll
        for (int dx = 0; dx < 3; ++dx) {
            uint wv = wpk[dy * 3 + dx];
            float wl = unlo(wv), wh = unhi(wv);
            #pragma unroll
            for (int k = 0; k < 7; ++k) {
                accA[k] = fmaf(fA[dx + k], wl, accA[k]);
                accB[k] = fmaf(fB[dx + k], wh, accB[k]);
            }
        }
    }

    const int ytok = y0 + r;
    #pragma unroll
    for (int k = 0; k < 7; ++k) {
        size_t tok = (size_t)b * NN + ytok * 56 + x0 + sg * 7 + k;
        float2 res = *(const float2*)(x + tok * CC + cA);
        float2 o = { accA[k] + res.x, accB[k] + res.y };
        *(float2*)(out + tok * CC + cA) = o;
    }
}

// ---------------- LayerNorm over C=256, wave-per-row, bf16 out ----------------
__global__ __launch_bounds__(256) void ln_kernel(
    const float* __restrict__ src, const float* __restrict__ g_all,
    const float* __restrict__ b_all, const int* __restrict__ dptr,
    ushort* __restrict__ dst)
{
    const int wid = threadIdx.x >> 6, lane = threadIdx.x & 63;
    const int row = blockIdx.x * 4 + wid;
    const int d = *dptr;
    const float* g = g_all + d * CC;
    const float* be = b_all + d * CC;
    const float* p = src + (size_t)row * CC;
    float4 v = *(const float4*)(p + lane * 4);
    float s = v.x + v.y + v.z + v.w;
    float sq = v.x*v.x + v.y*v.y + v.z*v.z + v.w*v.w;
    #pragma unroll
    for (int off = 1; off < 64; off <<= 1) {
        s  += __shfl_xor(s, off);
        sq += __shfl_xor(sq, off);
    }
    const float mean = s * (1.f / CC);
    const float var = sq * (1.f / CC) - mean * mean;
    const float rs = rsqrtf(var + 1e-5f);
    float4 g4 = *(const float4*)(g + lane * 4);
    float4 b4 = *(const float4*)(be + lane * 4);
    ushort4 o4;
    o4.x = f2bf((v.x - mean) * rs * g4.x + b4.x);
    o4.y = f2bf((v.y - mean) * rs * g4.y + b4.y);
    o4.z = f2bf((v.z - mean) * rs * g4.z + b4.z);
    o4.w = f2bf((v.w - mean) * rs * g4.w + b4.w);
    *(ushort4*)(dst + (size_t)row * CC + lane * 4) = o4;
}

// ---------------- bf16 MFMA GEMM: C = A[M][K] @ Bt[N][K]^T ----------------
template<int EPI>
__global__ __launch_bounds__(256) void gemm_mfma(
    const ushort* __restrict__ A, const ushort* __restrict__ Bt,
    const float* __restrict__ bias, const float* __restrict__ res,
    void* __restrict__ Cv, int M, int N, int K)
{
    __shared__ __align__(16) ushort Als[128 * 32];
    __shared__ __align__(16) ushort Bls[128 * 32];
    const int t = threadIdx.x;
    const int bm = blockIdx.y, bn = blockIdx.x;
    const int brow = bm * 128, bcol = bn * 128;
    const int lane = t & 63, w = t >> 6;
    const int wr = w >> 1, wc = w & 1;
    const int lrow = lane & 15, lko = (lane >> 4) * 8;

    const ushort* gA0 = A + (size_t)(brow + (t >> 2)) * K + (t & 3) * 8;
    const ushort* gA1 = gA0 + (size_t)64 * K;
    const ushort* gB0 = Bt + (size_t)(bcol + (t >> 2)) * K + (t & 3) * 8;
    const ushort* gB1 = gB0 + (size_t)64 * K;
    ushort* lA0 = &Als[t * 8];  ushort* lA1 = &Als[64 * 32 + t * 8];
    ushort* lB0 = &Bls[t * 8];  ushort* lB1 = &Bls[64 * 32 + t * 8];

    f32x4 acc[4][4] = {};

    for (int kt = 0; kt < K; kt += 32) {
        gload16(gA0 + kt, lA0);
        gload16(gA1 + kt, lA1);
        gload16(gB0 + kt, lB0);
        gload16(gB1 + kt, lB1);
        __syncthreads();
        bf16x8 af[4], bfr[4];
        #pragma unroll
        for (int i = 0; i < 4; ++i)
            af[i] = *(const bf16x8*)&Als[(wr * 64 + i * 16 + lrow) * 32 + lko];
        #pragma unroll
        for (int j = 0; j < 4; ++j)
            bfr[j] = *(const bf16x8*)&Bls[(wc * 64 + j * 16 + lrow) * 32 + lko];
        #pragma unroll
        for (int i = 0; i < 4; ++i)
            #pragma unroll
            for (int j = 0; j < 4; ++j)
                acc[i][j] = __builtin_amdgcn_mfma_f32_16x16x32_bf16(
                    af[i], bfr[j], acc[i][j], 0, 0, 0);
        __syncthreads();
    }

    float* Cf = (float*)Cv;
    ushort* Ch = (ushort*)Cv;
    #pragma unroll
    for (int j = 0; j < 4; ++j) {
        const int col = bcol + wc * 64 + j * 16 + lrow;
        const float bv = (EPI >= 2) ? bias[col] : 0.f;
        #pragma unroll
        for (int i = 0; i < 4; ++i) {
            const int row0 = brow + wr * 64 + i * 16 + (lane >> 4) * 4;
            #pragma unroll
            for (int r = 0; r < 4; ++r) {
                float v = acc[i][j][r] + bv;
                size_t off = (size_t)(row0 + r) * N + col;
                if (EPI == 2) {
                    v = 0.5f * v * (1.f + erff(v * 0.70710678118654752f));
                    Ch[off] = f2bf(v);
                } else if (EPI == 3) {
                    Cf[off] = v + res[off];
                } else {
                    Cf[off] = v;
                }
            }
        }
    }
}

// ---------------- k softmax: per-chunk column max + reduce ----------------
__global__ __launch_bounds__(256) void kmax1_kernel(
    const float* __restrict__ qkv, float* __restrict__ pmax)
{
    const int chunk = blockIdx.x, b = blockIdx.y, c = threadIdx.x;
    const float* kb = qkv + (size_t)(b * NN + chunk * 98) * 768 + 256 + c;
    float m = -3.4e38f;
    for (int i = 0; i < 98; ++i) m = fmaxf(m, kb[(size_t)i * 768]);
    pmax[(b * 32 + chunk) * CC + c] = m;
}

__global__ __launch_bounds__(256) void kmax2_kernel(
    const float* __restrict__ pmax, float* __restrict__ cmax)
{
    const int b = blockIdx.x, c = threadIdx.x;
    float m = -3.4e38f;
    #pragma unroll
    for (int i = 0; i < 32; ++i) m = fmaxf(m, pmax[(b * 32 + i) * CC + c]);
    cmax[b * CC + c] = m;
}

// ---------------- kv partial: per-chunk exp-weighted sums ----------------
__global__ __launch_bounds__(256) void kvacc_kernel(
    const float* __restrict__ qkv, const float* __restrict__ cmax,
    float* __restrict__ partial, float* __restrict__ psum)
{
    const int chunk = blockIdx.x, h = blockIdx.y, b = blockIdx.z;
    const int t = threadIdx.x;
    const int ck = t & 31, g = t >> 5;
    const int n0 = chunk * 196;
    const float* kb = qkv + (size_t)(b * NN + n0) * 768 + 256 + h * 32 + ck;
    const float* vb = qkv + (size_t)(b * NN + n0) * 768 + 512 + h * 32 + g * 4;
    const float cm = cmax[b * CC + h * 32 + ck];
    float a0 = 0.f, a1 = 0.f, a2 = 0.f, a3 = 0.f, s = 0.f;
    for (int i = 0; i < 196; ++i) {
        float e = __expf(kb[(size_t)i * 768] - cm);
        float4 v4 = *(const float4*)(vb + (size_t)i * 768);
        a0 += e * v4.x; a1 += e * v4.y; a2 += e * v4.z; a3 += e * v4.w;
        s += e;
    }
    float4 o = {a0, a1, a2, a3};
    *(float4*)(partial + ((((size_t)chunk * 8 + b) * 8 + h) * 32 + ck) * 32 + g * 4) = o;
    if (g == 0) psum[((chunk * 8 + b) * 8 + h) * 32 + ck] = s;
}

__global__ __launch_bounds__(256) void kvnorm_kernel(
    const float* __restrict__ partial, const float* __restrict__ psum,
    float* __restrict__ kv)
{
    const int idx = blockIdx.x * 256 + threadIdx.x;   // [b][h][ck][cv]
    const int ckidx = idx >> 5;
    float sum = 0.f, cs = 0.f;
    #pragma unroll
    for (int ch = 0; ch < 16; ++ch) {
        sum += partial[(size_t)ch * 65536 + idx];
        cs  += psum[ch * 2048 + ckidx];
    }
    kv[idx] = sum / cs;
}

// ---------------- fa GEMM: fa[b,h] = q[b,:,h] @ kv[b,h]  (into k-slot) ------
__global__ __launch_bounds__(256) void fa_kernel(
    float* __restrict__ qkv, const float* __restrict__ kvb)
{
    const int mt = blockIdx.x, h = blockIdx.y, b = blockIdx.z;
    const int t = threadIdx.x;
    const int lane = t & 63, wv = t >> 6;
    const int row0 = mt * 448 + wv * 112;
    const int lr = lane & 15, lk = (lane >> 4) * 8;

    bf16x8 bfr[2];
    #pragma unroll
    for (int jj = 0; jj < 2; ++jj)
        #pragma unroll
        for (int e = 0; e < 8; ++e)
            bfr[jj][e] = (short)f2bf(kvb[((size_t)(b * 8 + h) * 32 + lk + e) * 32 + jj * 16 + lr]);

    #pragma unroll
    for (int i = 0; i < 7; ++i) {
        size_t tok = (size_t)b * NN + row0 + i * 16 + lr;
        const float* qp = qkv + tok * 768 + h * 32 + lk;
        float4 qa = *(const float4*)qp;
        float4 qb2 = *(const float4*)(qp + 4);
        bf16x8 af;
        af[0] = (short)f2bf(qa.x);  af[1] = (short)f2bf(qa.y);
        af[2] = (short)f2bf(qa.z);  af[3] = (short)f2bf(qa.w);
        af[4] = (short)f2bf(qb2.x); af[5] = (short)f2bf(qb2.y);
        af[6] = (short)f2bf(qb2.z); af[7] = (short)f2bf(qb2.w);
        f32x4 a0 = {0.f, 0.f, 0.f, 0.f}, a1 = {0.f, 0.f, 0.f, 0.f};
        a0 = __builtin_amdgcn_mfma_f32_16x16x32_bf16(af, bfr[0], a0, 0, 0, 0);
        a1 = __builtin_amdgcn_mfma_f32_16x16x32_bf16(af, bfr[1], a1, 0, 0, 0);
        #pragma unroll
        for (int r = 0; r < 4; ++r) {
            size_t trow = (size_t)b * NN + row0 + i * 16 + (lane >> 4) * 4 + r;
            qkv[trow * 768 + 256 + h * 32 + lr]      = a0[r];
            qkv[trow * 768 + 256 + h * 32 + 16 + lr] = a1[r];
        }
    }
}

// ---------------- domain gating ----------------
__global__ __launch_bounds__(256) void da_kernel(
    const float* __restrict__ dl, const float* __restrict__ w1,
    const float* __restrict__ b1, const float* __restrict__ w2,
    const float* __restrict__ b2, float* __restrict__ da)
{
    const int b = blockIdx.x, t = threadIdx.x;
    __shared__ float r[HID];
    __shared__ float raw[CC];
    if (t < HID) {
        float s = b1[t];
        #pragma unroll
        for (int k = 0; k < 4; ++k) s += dl[b * 4 + k] * w1[k * HID + t];
        r[t] = fmaxf(s, 0.f);
    }
    __syncthreads();
    float s = b2[t];
    for (int j = 0; j < HID; ++j) s += r[j] * w2[j * CC + t];
    raw[t] = s;
    __syncthreads();
    const int ch = t & 31;
    float m = -3.4e38f;
    #pragma unroll
    for (int hh = 0; hh < NH; ++hh) m = fmaxf(m, raw[hh * 32 + ch]);
    float ssum = 0.f;
    #pragma unroll
    for (int hh = 0; hh < NH; ++hh) ssum += __expf(raw[hh * 32 + ch] - m);
    da[b * CC + t] = __expf(raw[t] - m) / ssum;
}

// ---------------- combine: conv + fa + gating (sliding window) -------------
template<int KS>
__device__ __forceinline__ void comb_body(
    uint* vt, int qq,
    const float* __restrict__ qkv, const float* __restrict__ da,
    const float* __restrict__ w3, const float* __restrict__ b3,
    const float* __restrict__ w5, const float* __restrict__ b5,
    const float* __restrict__ w7, const float* __restrict__ b7,
    ushort* __restrict__ out)
{
    constexpr int R = KS / 2;
    constexpr int TR = KS + 1;
    constexpr int WCOLS = 7 + 2 * R;
    const int hx = blockIdx.x & 1;
    const int y0 = blockIdx.y * 2, b = blockIdx.z;
    const int x0 = hx * 28;
    const int t = threadIdx.x;
    const int c0 = qq * 64;

    // stage TR rows x 34 cols x 64 ch (pairs 2p,2p+1), zero-padded
    {
        const int cw = t & 15, cg = t >> 4;
        for (int pos = cw; pos < TR * 34; pos += 16) {
            int row = pos / 34, col = pos - row * 34;
            int gy = y0 + row - R, gx = x0 + col - 3;
            float4 v = {0.f, 0.f, 0.f, 0.f};
            if ((unsigned)gy < 56u && (unsigned)gx < 56u)
                v = *(const float4*)(qkv + ((size_t)b * NN + gy * 56 + gx) * 768 + 512 + c0 + cg * 4);
            uint2 pk = { pk2(v.x, v.y), pk2(v.z, v.w) };
            *(uint2*)&vt[pos * 32 + cg * 2] = pk;
        }
    }
    const int p = t & 31, rseg = t >> 5;
    const int r = rseg >> 2, sg = rseg & 3;
    const int cA = c0 + 2 * p;
    // per-lane weight selection (q2 block mixes 5x5 and 7x7 lanes)
    int rK; const float* wbA; const float* wbB; float cbA, cbB;
    if (cA < 64)       { rK = 1; wbA = w3 + cA * 9;          wbB = wbA + 9;  cbA = b3[cA];       cbB = b3[cA + 1]; }
    else if (cA < 160) { rK = 2; wbA = w5 + (cA - 64) * 25;  wbB = wbA + 25; cbA = b5[cA - 64];  cbB = b5[cA - 63]; }
    else               { rK = 3; wbA = w7 + (cA - 160) * 49; wbB = wbA + 49; cbA = b7[cA - 160]; cbB = b7[cA - 159]; }
    const int kslo = 2 * rK + 1, offp = R - rK;
    uint wpk[KS * KS];
    #pragma unroll
    for (int dy = 0; dy < KS; ++dy)
        #pragma unroll
        for (int dx = 0; dx < KS; ++dx) {
            float lo = 0.f, hi = 0.f;
            int sy = dy - offp, sx = dx - offp;
            if (sy >= 0 && sy < kslo && sx >= 0 && sx < kslo) {
                lo = wbA[sy * kslo + sx];
                hi = wbB[sy * kslo + sx];
            }
            wpk[dy * KS + dx] = pk2(lo, hi);
        }
    __syncthreads();

    float accA[7], accB[7];
    #pragma unroll
    for (int k = 0; k < 7; ++k) { accA[k] = cbA; accB[k] = cbB; }

    #pragma unroll
    for (int dy = 0; dy < KS; ++dy) {
        const int rowbase = (r + dy) * 34 * 32;
        float fA[WCOLS], fB[WCOLS];
        #pragma unroll
        for (int u = 0; u < WCOLS; ++u) {
            uint vv = vt[rowbase + (sg * 7 + 3 - R + u) * 32 + p];
            fA[u] = unlo(vv); fB[u] = unhi(vv);
        }
        #pragma unroll
        for (int dx = 0; dx < KS; ++dx) {
            uint wv = wpk[dy * KS + dx];
            float wl = unlo(wv), wh = unhi(wv);
            #pragma unroll
            for (int k = 0; k < 7; ++k) {
                accA[k] = fmaf(fA[dx + k], wl, accA[k]);
                accB[k] = fmaf(fB[dx + k], wh, accB[k]);
            }
        }
    }

    const float daA = da[b * CC + cA], daB = da[b * CC + cA + 1];
    const int ytok = y0 + r;
    #pragma unroll
    for (int k = 0; k < 7; ++k) {
        size_t tok = (size_t)b * NN + ytok * 56 + x0 + sg * 7 + k;
        float2 q2 = *(const float2*)(qkv + tok * 768 + cA);
        float2 fa2 = *(const float2*)(qkv + tok * 768 + 256 + cA);
        ushort2 o = { f2bf(daA * (SCALE * fa2.x + q2.x * accA[k])),
                      f2bf(daB * (SCALE * fa2.y + q2.y * accB[k])) };
        *(ushort2*)(out + tok * CC + cA) = o;
    }
}

__global__ __launch_bounds__(256) void combine_kernel(
    const float* __restrict__ qkv, const float* __restrict__ da,
    const float* __restrict__ w3, const float* __restrict__ b3,
    const float* __restrict__ w5, const float* __restrict__ b5,
    const float* __restrict__ w7, const float* __restrict__ b7,
    ushort* __restrict__ out)
{
    __shared__ uint vt[8 * 34 * 32];
    switch (blockIdx.x >> 1) {
    case 0:  comb_body<3>(vt, 0, qkv, da, w3, b3, w5, b5, w7, b7, out); break;
    case 1:  comb_body<5>(vt, 1, qkv, da, w3, b3, w5, b5, w7, b7, out); break;
    case 2:  comb_body<7>(vt, 2, qkv, da, w3, b3, w5, b5, w7, b7, out); break;
    default: comb_body<7>(vt, 3, qkv, da, w3, b3, w5, b5, w7, b7, out); break;
    }
}

// ---------------- launch ----------------
extern "C" void kernel_launch(void* const* d_in, const int* in_sizes, int n_in,
                              void* d_out, int out_size, void* d_ws, size_t ws_size,
                              hipStream_t stream)
{
    const float* x       = (const float*)d_in[0];
    const float* dlab    = (const float*)d_in[1];
    const float* cpe_w   = (const float*)d_in[2];
    const float* cpe_b   = (const float*)d_in[3];
    const float* ln1_g   = (const float*)d_in[4];
    const float* ln1_b   = (const float*)d_in[5];
    const float* qkv_w   = (const float*)d_in[6];
    const float* proj_w  = (const float*)d_in[7];
    const float* proj_b  = (const float*)d_in[8];
    const float* dl_w1   = (const float*)d_in[9];
    const float* dl_b1   = (const float*)d_in[10];
    const float* dl_w2   = (const float*)d_in[11];
    const float* dl_b2   = (const float*)d_in[12];
    const float* crpe_w3 = (const float*)d_in[13];
    const float* crpe_b3 = (const float*)d_in[14];
    const float* crpe_w5 = (const float*)d_in[15];
    const float* crpe_b5 = (const float*)d_in[16];
    const float* crpe_w7 = (const float*)d_in[17];
    const float* crpe_b7 = (const float*)d_in[18];
    const float* ln2_g   = (const float*)d_in[19];
    const float* ln2_b   = (const float*)d_in[20];
    const float* fc1_w   = (const float*)d_in[21];
    const float* fc1_b   = (const float*)d_in[22];
    const float* fc2_w   = (const float*)d_in[23];
    const float* fc2_b   = (const float*)d_in[24];
    const int*   dptr    = (const int*)d_in[27];

    float* out = (float*)d_out;
    char* W = (char*)d_ws;
    size_t off = 0;
    float* x1 = (float*)(W + off);          off += (size_t)NT * CC * 4;   // f32 [NT,C]
    float* qkv = (float*)(W + off);                                        // f32 [NT,768]
    ushort* hidden = (ushort*)qkv;                                         // overlay: bf16 [NT,1024]
    off += (size_t)NT * 768 * 4;
    ushort* actbf = (ushort*)(W + off);     off += (size_t)NT * CC * 2;   // bf16 [NT,C]
    // overlay: kv partials live only between qkv-GEMM and fa, while actbf is dead
    float* partial = (float*)actbf;                    // 16*65536 f32 = 4 MB
    float* psum = partial + (size_t)16 * 65536;        // 32768 f32
    float* kvb = (float*)(W + off);         off += (size_t)65536 * 4;
    float* dab = (float*)(W + off);         off += (size_t)BB * CC * 4;
    float* pmax = (float*)(W + off);        off += (size_t)BB * 32 * CC * 4;
    float* cmax = (float*)(W + off);        off += (size_t)BB * CC * 4;
    ushort* wq  = (ushort*)(W + off);       off += (size_t)768 * 256 * 2;
    ushort* wp  = (ushort*)(W + off);       off += (size_t)256 * 256 * 2;
    ushort* w1t = (ushort*)(W + off);       off += (size_t)1024 * 256 * 2;
    ushort* w2t = (ushort*)(W + off);       off += (size_t)256 * 1024 * 2;

    // 0. weight transpose+cast (tiled)
    hipLaunchKernelGGL(wtrans_kernel, dim3(768 / 32, 256 / 32), dim3(256), 0, stream, qkv_w, wq, 256, 768);
    hipLaunchKernelGGL(wtrans_kernel, dim3(256 / 32, 256 / 32), dim3(256), 0, stream, proj_w, wp, 256, 256);
    hipLaunchKernelGGL(wtrans_kernel, dim3(1024 / 32, 256 / 32), dim3(256), 0, stream, fc1_w, w1t, 256, 1024);
    hipLaunchKernelGGL(wtrans_kernel, dim3(256 / 32, 1024 / 32), dim3(256), 0, stream, fc2_w, w2t, 1024, 256);
    // 1. CPE -> x1 (f32)
    hipLaunchKernelGGL(cpe_kernel, dim3(8, 28, 8), dim3(256), 0, stream, x, cpe_w, cpe_b, x1);
    // 2. domain gating
    hipLaunchKernelGGL(da_kernel, dim3(BB), dim3(256), 0, stream,
                       dlab, dl_w1, dl_b1, dl_w2, dl_b2, dab);
    // 3. LN1 -> actbf (bf16)
    hipLaunchKernelGGL(ln_kernel, dim3(NT / 4), dim3(256), 0, stream,
                       x1, ln1_g, ln1_b, dptr, actbf);
    // 4. qkv GEMM: [NT,256]bf16 @ [768,256]^T -> qkv f32
    hipLaunchKernelGGL(gemm_mfma<0>, dim3(768 / 128, NT / 128), dim3(256), 0, stream,
                       actbf, wq, nullptr, nullptr, (void*)qkv, NT, 768, 256);
    // 5. k column max (chunked) + reduce
    hipLaunchKernelGGL(kmax1_kernel, dim3(32, 8), dim3(256), 0, stream, qkv, pmax);
    hipLaunchKernelGGL(kmax2_kernel, dim3(8), dim3(256), 0, stream, pmax, cmax);
    // 6. kv partial sums + normalize
    hipLaunchKernelGGL(kvacc_kernel, dim3(16, 8, 8), dim3(256), 0, stream,
                       qkv, cmax, partial, psum);
    hipLaunchKernelGGL(kvnorm_kernel, dim3(256), dim3(256), 0, stream,
                       partial, psum, kvb);
    // 7. fa = q @ kv -> written into qkv's k-slot (k is dead now)
    hipLaunchKernelGGL(fa_kernel, dim3(7, 8, 8), dim3(256), 0, stream, qkv, kvb);
    // 8. combine (conv + fa + gating) -> actbf (bf16)
    hipLaunchKernelGGL(combine_kernel, dim3(8, 28, 8), dim3(256), 0, stream,
                       qkv, dab, crpe_w3, crpe_b3, crpe_w5, crpe_b5,
                       crpe_w7, crpe_b7, actbf);
    // 9. proj GEMM + bias + residual(x1) -> d_out f32
    hipLaunchKernelGGL(gemm_mfma<3>, dim3(256 / 128, NT / 128), dim3(256), 0, stream,
                       actbf, wp, proj_b, x1, (void*)out, NT, 256, 256);
    // 10. LN2 -> actbf (bf16)
    hipLaunchKernelGGL(ln_kernel, dim3(NT / 4), dim3(256), 0, stream,
                       out, ln2_g, ln2_b, dptr, actbf);
    // 11. fc1 + gelu -> hidden (bf16)
    hipLaunchKernelGGL(gemm_mfma<2>, dim3(1024 / 128, NT / 128), dim3(256), 0, stream,
                       actbf, w1t, fc1_b, nullptr, (void*)hidden, NT, 1024, 256);
    // 12. fc2 + bias + residual(d_out) -> d_out f32
    hipLaunchKernelGGL(gemm_mfma<3>, dim3(256 / 128, NT / 128), dim3(256), 0, stream,
                       hidden, w2t, fc2_b, out, (void*)out, NT, 256, 1024);
}

// Round 6
// 426.154 us; speedup vs baseline: 1.0303x; 1.0303x over previous
//
#include <hip/hip_runtime.h>
#include <hip/hip_bf16.h>
#include <math.h>

// Problem constants (fixed by setup_inputs)
#define BB 8
#define HH 56
#define WW 56
#define NN (HH*WW)          // 3136
#define CC 256
#define NH 8
#define NT (BB*NN)          // 25088
#define HID 128
#define MH 1024
#define SCALE 0.17677669529663687f   // 32^-0.5

typedef __attribute__((ext_vector_type(8))) short bf16x8;
typedef __attribute__((ext_vector_type(4))) float f32x4;

__device__ __forceinline__ ushort f2bf(float f) {
    __hip_bfloat16 h = __float2bfloat16(f);
    return *(ushort*)&h;
}
__device__ __forceinline__ uint pk2(float lo, float hi) {
    return ((uint)f2bf(hi) << 16) | (uint)f2bf(lo);
}
__device__ __forceinline__ float unlo(uint u) { return __uint_as_float(u << 16); }
__device__ __forceinline__ float unhi(uint u) { return __uint_as_float(u & 0xFFFF0000u); }

__device__ __forceinline__ void gload16(const void* g, void* s) {
    __builtin_amdgcn_global_load_lds(
        (const __attribute__((address_space(1))) void*)g,
        (__attribute__((address_space(3))) void*)s, 16, 0, 0);
}

// ---------------- weight transpose + f32->bf16: w[K][N] -> wt[N][K] --------
__global__ __launch_bounds__(256) void wtrans_kernel(
    const float* __restrict__ w, ushort* __restrict__ wt, int K, int N)
{
    __shared__ float tile[32][33];
    const int t = threadIdx.x;
    const int col = t & 31, rw = t >> 5;
    const int k0 = blockIdx.y * 32, n0 = blockIdx.x * 32;
    #pragma unroll
    for (int i = rw; i < 32; i += 8)
        tile[i][col] = w[(size_t)(k0 + i) * N + n0 + col];
    __syncthreads();
    #pragma unroll
    for (int i = rw; i < 32; i += 8)
        wt[(size_t)(n0 + i) * K + k0 + col] = f2bf(tile[col][i]);
}

// ---------------- pack CRPE weights: [qq][49][32] bf16-pairs ----------------
__global__ __launch_bounds__(256) void wpack_kernel(
    const float* __restrict__ w3, const float* __restrict__ b3,
    const float* __restrict__ w5, const float* __restrict__ b5,
    const float* __restrict__ w7, const float* __restrict__ b7,
    uint* __restrict__ wt, float* __restrict__ bt)
{
    const int qq = blockIdx.x;
    const int KSQ = (qq == 0) ? 3 : (qq == 1) ? 5 : 7;
    for (int idx = threadIdx.x; idx < 49 * 32; idx += 256) {
        int tap = idx >> 5, p = idx & 31;
        int cA = qq * 64 + 2 * p;
        float lo = 0.f, hi = 0.f;
        if (tap < KSQ * KSQ) {
            int dy = tap / KSQ, dx = tap - dy * KSQ;
            const float* wb; int kslo;
            if (cA < 64)       { wb = w3 + cA * 9;          kslo = 3; }
            else if (cA < 160) { wb = w5 + (cA - 64) * 25;  kslo = 5; }
            else               { wb = w7 + (cA - 160) * 49; kslo = 7; }
            int offp = KSQ / 2 - kslo / 2;
            int sy = dy - offp, sx = dx - offp;
            if (sy >= 0 && sy < kslo && sx >= 0 && sx < kslo) {
                lo = wb[sy * kslo + sx];
                hi = wb[kslo * kslo + sy * kslo + sx];
            }
        }
        wt[(qq * 49 + tap) * 32 + p] = pk2(lo, hi);
    }
    if (threadIdx.x < 32) {
        int p = threadIdx.x, cA = qq * 64 + 2 * p;
        float blo, bhi;
        if (cA < 64)       { blo = b3[cA];       bhi = b3[cA + 1]; }
        else if (cA < 160) { blo = b5[cA - 64];  bhi = b5[cA - 63]; }
        else               { blo = b7[cA - 160]; bhi = b7[cA - 159]; }
        bt[(qq * 32 + p) * 2]     = blo;
        bt[(qq * 32 + p) * 2 + 1] = bhi;
    }
}

// ---------------- pack CPE weights: [qq][9][32] bf16-pairs ----------------
__global__ __launch_bounds__(256) void cpack_kernel(
    const float* __restrict__ w, const float* __restrict__ bias,
    uint* __restrict__ wt, float* __restrict__ bt)
{
    const int qq = blockIdx.x;
    for (int idx = threadIdx.x; idx < 9 * 32; idx += 256) {
        int tap = idx >> 5, p = idx & 31;
        int cA = qq * 64 + 2 * p;
        wt[(qq * 9 + tap) * 32 + p] = pk2(w[cA * 9 + tap], w[(cA + 1) * 9 + tap]);
    }
    if (threadIdx.x < 32) {
        int p = threadIdx.x, cA = qq * 64 + 2 * p;
        bt[(qq * 32 + p) * 2]     = bias[cA];
        bt[(qq * 32 + p) * 2 + 1] = bias[cA + 1];
    }
}

// ---------------- CPE: depthwise 3x3 + bias + residual (sliding window) ----
__global__ __launch_bounds__(256) void cpe_kernel(
    const float* __restrict__ x, const uint* __restrict__ wtab,
    const float* __restrict__ btab, float* __restrict__ out)
{
    __shared__ uint vt[4 * 34 * 32];
    const int qq = blockIdx.x >> 1, hx = blockIdx.x & 1;
    const int y0 = blockIdx.y * 2, b = blockIdx.z;
    const int x0 = hx * 28;
    const int t = threadIdx.x;
    const int c0 = qq * 64;
    const int p = t & 31;

    uint wpk[9];
    #pragma unroll
    for (int i = 0; i < 9; ++i) wpk[i] = wtab[(qq * 9 + i) * 32 + p];
    const float2 bb = *(const float2*)(btab + (qq * 32 + p) * 2);

    // stage 4 rows x 34 cols, one bf16-pair per lane per position (bank = p)
    for (int pos = t >> 5; pos < 4 * 34; pos += 8) {
        int row = pos / 34, col = pos - row * 34;
        int gy = y0 + row - 1, gx = x0 + col - 3;
        float2 v = {0.f, 0.f};
        if ((unsigned)gy < 56u && (unsigned)gx < 56u)
            v = *(const float2*)(x + ((size_t)b * NN + gy * 56 + gx) * CC + c0 + 2 * p);
        vt[pos * 32 + p] = pk2(v.x, v.y);
    }
    __syncthreads();

    const int rseg = t >> 5;
    const int r = rseg >> 2, sg = rseg & 3;
    float accA[7], accB[7];
    #pragma unroll
    for (int k = 0; k < 7; ++k) { accA[k] = bb.x; accB[k] = bb.y; }

    #pragma unroll
    for (int dy = 0; dy < 3; ++dy) {
        const int rowbase = (r + dy) * 34 * 32;
        float fA[9], fB[9];
        #pragma unroll
        for (int u = 0; u < 9; ++u) {
            uint vv = vt[rowbase + (sg * 7 + 2 + u) * 32 + p];
            fA[u] = unlo(vv); fB[u] = unhi(vv);
        }
        #pragma unroll
        for (int dx = 0; dx < 3; ++dx) {
            uint wv = wpk[dy * 3 + dx];
            float wl = unlo(wv), wh = unhi(wv);
            #pragma unroll
            for (int k = 0; k < 7; ++k) {
                accA[k] = fmaf(fA[dx + k], wl, accA[k]);
                accB[k] = fmaf(fB[dx + k], wh, accB[k]);
            }
        }
    }

    const int cA = c0 + 2 * p;
    const int ytok = y0 + r;
    #pragma unroll
    for (int k = 0; k < 7; ++k) {
        size_t tok = (size_t)b * NN + ytok * 56 + x0 + sg * 7 + k;
        float2 res = *(const float2*)(x + tok * CC + cA);
        float2 o = { accA[k] + res.x, accB[k] + res.y };
        *(float2*)(out + tok * CC + cA) = o;
    }
}

// ---------------- LayerNorm over C=256, wave-per-row, bf16 out ----------------
__global__ __launch_bounds__(256) void ln_kernel(
    const float* __restrict__ src, const float* __restrict__ g_all,
    const float* __restrict__ b_all, const int* __restrict__ dptr,
    ushort* __restrict__ dst)
{
    const int wid = threadIdx.x >> 6, lane = threadIdx.x & 63;
    const int row = blockIdx.x * 4 + wid;
    const int d = *dptr;
    const float* g = g_all + d * CC;
    const float* be = b_all + d * CC;
    const float* p = src + (size_t)row * CC;
    float4 v = *(const float4*)(p + lane * 4);
    float s = v.x + v.y + v.z + v.w;
    float sq = v.x*v.x + v.y*v.y + v.z*v.z + v.w*v.w;
    #pragma unroll
    for (int off = 1; off < 64; off <<= 1) {
        s  += __shfl_xor(s, off);
        sq += __shfl_xor(sq, off);
    }
    const float mean = s * (1.f / CC);
    const float var = sq * (1.f / CC) - mean * mean;
    const float rs = rsqrtf(var + 1e-5f);
    float4 g4 = *(const float4*)(g + lane * 4);
    float4 b4 = *(const float4*)(be + lane * 4);
    ushort4 o4;
    o4.x = f2bf((v.x - mean) * rs * g4.x + b4.x);
    o4.y = f2bf((v.y - mean) * rs * g4.y + b4.y);
    o4.z = f2bf((v.z - mean) * rs * g4.z + b4.z);
    o4.w = f2bf((v.w - mean) * rs * g4.w + b4.w);
    *(ushort4*)(dst + (size_t)row * CC + lane * 4) = o4;
}

// ---------------- bf16 MFMA GEMM: C = A[M][K] @ Bt[N][K]^T ----------------
template<int EPI>
__global__ __launch_bounds__(256) void gemm_mfma(
    const ushort* __restrict__ A, const ushort* __restrict__ Bt,
    const float* __restrict__ bias, const float* __restrict__ res,
    void* __restrict__ Cv, int M, int N, int K)
{
    __shared__ __align__(16) ushort Als[128 * 32];
    __shared__ __align__(16) ushort Bls[128 * 32];
    const int t = threadIdx.x;
    const int bm = blockIdx.y, bn = blockIdx.x;
    const int brow = bm * 128, bcol = bn * 128;
    const int lane = t & 63, w = t >> 6;
    const int wr = w >> 1, wc = w & 1;
    const int lrow = lane & 15, lko = (lane >> 4) * 8;

    const ushort* gA0 = A + (size_t)(brow + (t >> 2)) * K + (t & 3) * 8;
    const ushort* gA1 = gA0 + (size_t)64 * K;
    const ushort* gB0 = Bt + (size_t)(bcol + (t >> 2)) * K + (t & 3) * 8;
    const ushort* gB1 = gB0 + (size_t)64 * K;
    ushort* lA0 = &Als[t * 8];  ushort* lA1 = &Als[64 * 32 + t * 8];
    ushort* lB0 = &Bls[t * 8];  ushort* lB1 = &Bls[64 * 32 + t * 8];

    f32x4 acc[4][4] = {};

    for (int kt = 0; kt < K; kt += 32) {
        gload16(gA0 + kt, lA0);
        gload16(gA1 + kt, lA1);
        gload16(gB0 + kt, lB0);
        gload16(gB1 + kt, lB1);
        __syncthreads();
        bf16x8 af[4], bfr[4];
        #pragma unroll
        for (int i = 0; i < 4; ++i)
            af[i] = *(const bf16x8*)&Als[(wr * 64 + i * 16 + lrow) * 32 + lko];
        #pragma unroll
        for (int j = 0; j < 4; ++j)
            bfr[j] = *(const bf16x8*)&Bls[(wc * 64 + j * 16 + lrow) * 32 + lko];
        #pragma unroll
        for (int i = 0; i < 4; ++i)
            #pragma unroll
            for (int j = 0; j < 4; ++j)
                acc[i][j] = __builtin_amdgcn_mfma_f32_16x16x32_bf16(
                    af[i], bfr[j], acc[i][j], 0, 0, 0);
        __syncthreads();
    }

    float* Cf = (float*)Cv;
    ushort* Ch = (ushort*)Cv;
    #pragma unroll
    for (int j = 0; j < 4; ++j) {
        const int col = bcol + wc * 64 + j * 16 + lrow;
        const float bv = (EPI >= 2) ? bias[col] : 0.f;
        #pragma unroll
        for (int i = 0; i < 4; ++i) {
            const int row0 = brow + wr * 64 + i * 16 + (lane >> 4) * 4;
            #pragma unroll
            for (int r = 0; r < 4; ++r) {
                float v = acc[i][j][r] + bv;
                size_t off = (size_t)(row0 + r) * N + col;
                if (EPI == 2) {
                    v = 0.5f * v * (1.f + erff(v * 0.70710678118654752f));
                    Ch[off] = f2bf(v);
                } else if (EPI == 3) {
                    Cf[off] = v + res[off];
                } else {
                    Cf[off] = v;
                }
            }
        }
    }
}

// ---------------- k softmax: per-chunk column max + reduce ----------------
__global__ __launch_bounds__(256) void kmax1_kernel(
    const float* __restrict__ qkv, float* __restrict__ pmax)
{
    const int chunk = blockIdx.x, b = blockIdx.y, c = threadIdx.x;
    const float* kb = qkv + (size_t)(b * NN + chunk * 98) * 768 + 256 + c;
    float m = -3.4e38f;
    for (int i = 0; i < 98; ++i) m = fmaxf(m, kb[(size_t)i * 768]);
    pmax[(b * 32 + chunk) * CC + c] = m;
}

__global__ __launch_bounds__(256) void kmax2_kernel(
    const float* __restrict__ pmax, float* __restrict__ cmax)
{
    const int b = blockIdx.x, c = threadIdx.x;
    float m = -3.4e38f;
    #pragma unroll
    for (int i = 0; i < 32; ++i) m = fmaxf(m, pmax[(b * 32 + i) * CC + c]);
    cmax[b * CC + c] = m;
}

// ---------------- kv partial: per-chunk exp-weighted sums ----------------
__global__ __launch_bounds__(256) void kvacc_kernel(
    const float* __restrict__ qkv, const float* __restrict__ cmax,
    float* __restrict__ partial, float* __restrict__ psum)
{
    const int chunk = blockIdx.x, h = blockIdx.y, b = blockIdx.z;
    const int t = threadIdx.x;
    const int ck = t & 31, g = t >> 5;
    const int n0 = chunk * 196;
    const float* kb = qkv + (size_t)(b * NN + n0) * 768 + 256 + h * 32 + ck;
    const float* vb = qkv + (size_t)(b * NN + n0) * 768 + 512 + h * 32 + g * 4;
    const float cm = cmax[b * CC + h * 32 + ck];
    float a0 = 0.f, a1 = 0.f, a2 = 0.f, a3 = 0.f, s = 0.f;
    for (int i = 0; i < 196; ++i) {
        float e = __expf(kb[(size_t)i * 768] - cm);
        float4 v4 = *(const float4*)(vb + (size_t)i * 768);
        a0 += e * v4.x; a1 += e * v4.y; a2 += e * v4.z; a3 += e * v4.w;
        s += e;
    }
    float4 o = {a0, a1, a2, a3};
    *(float4*)(partial + ((((size_t)chunk * 8 + b) * 8 + h) * 32 + ck) * 32 + g * 4) = o;
    if (g == 0) psum[((chunk * 8 + b) * 8 + h) * 32 + ck] = s;
}

__global__ __launch_bounds__(256) void kvnorm_kernel(
    const float* __restrict__ partial, const float* __restrict__ psum,
    float* __restrict__ kv)
{
    const int idx = blockIdx.x * 256 + threadIdx.x;   // [b][h][ck][cv]
    const int ckidx = idx >> 5;
    float sum = 0.f, cs = 0.f;
    #pragma unroll
    for (int ch = 0; ch < 16; ++ch) {
        sum += partial[(size_t)ch * 65536 + idx];
        cs  += psum[ch * 2048 + ckidx];
    }
    kv[idx] = sum / cs;
}

// ---------------- fa GEMM: fa[b,h] = q[b,:,h] @ kv[b,h]  (into k-slot) ------
__global__ __launch_bounds__(256) void fa_kernel(
    float* __restrict__ qkv, const float* __restrict__ kvb)
{
    const int mt = blockIdx.x, h = blockIdx.y, b = blockIdx.z;
    const int t = threadIdx.x;
    const int lane = t & 63, wv = t >> 6;
    const int row0 = mt * 448 + wv * 112;
    const int lr = lane & 15, lk = (lane >> 4) * 8;

    bf16x8 bfr[2];
    #pragma unroll
    for (int jj = 0; jj < 2; ++jj)
        #pragma unroll
        for (int e = 0; e < 8; ++e)
            bfr[jj][e] = (short)f2bf(kvb[((size_t)(b * 8 + h) * 32 + lk + e) * 32 + jj * 16 + lr]);

    #pragma unroll
    for (int i = 0; i < 7; ++i) {
        size_t tok = (size_t)b * NN + row0 + i * 16 + lr;
        const float* qp = qkv + tok * 768 + h * 32 + lk;
        float4 qa = *(const float4*)qp;
        float4 qb2 = *(const float4*)(qp + 4);
        bf16x8 af;
        af[0] = (short)f2bf(qa.x);  af[1] = (short)f2bf(qa.y);
        af[2] = (short)f2bf(qa.z);  af[3] = (short)f2bf(qa.w);
        af[4] = (short)f2bf(qb2.x); af[5] = (short)f2bf(qb2.y);
        af[6] = (short)f2bf(qb2.z); af[7] = (short)f2bf(qb2.w);
        f32x4 a0 = {0.f, 0.f, 0.f, 0.f}, a1 = {0.f, 0.f, 0.f, 0.f};
        a0 = __builtin_amdgcn_mfma_f32_16x16x32_bf16(af, bfr[0], a0, 0, 0, 0);
        a1 = __builtin_amdgcn_mfma_f32_16x16x32_bf16(af, bfr[1], a1, 0, 0, 0);
        #pragma unroll
        for (int r = 0; r < 4; ++r) {
            size_t trow = (size_t)b * NN + row0 + i * 16 + (lane >> 4) * 4 + r;
            qkv[trow * 768 + 256 + h * 32 + lr]      = a0[r];
            qkv[trow * 768 + 256 + h * 32 + 16 + lr] = a1[r];
        }
    }
}

// ---------------- domain gating ----------------
__global__ __launch_bounds__(256) void da_kernel(
    const float* __restrict__ dl, const float* __restrict__ w1,
    const float* __restrict__ b1, const float* __restrict__ w2,
    const float* __restrict__ b2, float* __restrict__ da)
{
    const int b = blockIdx.x, t = threadIdx.x;
    __shared__ float r[HID];
    __shared__ float raw[CC];
    if (t < HID) {
        float s = b1[t];
        #pragma unroll
        for (int k = 0; k < 4; ++k) s += dl[b * 4 + k] * w1[k * HID + t];
        r[t] = fmaxf(s, 0.f);
    }
    __syncthreads();
    float s = b2[t];
    for (int j = 0; j < HID; ++j) s += r[j] * w2[j * CC + t];
    raw[t] = s;
    __syncthreads();
    const int ch = t & 31;
    float m = -3.4e38f;
    #pragma unroll
    for (int hh = 0; hh < NH; ++hh) m = fmaxf(m, raw[hh * 32 + ch]);
    float ssum = 0.f;
    #pragma unroll
    for (int hh = 0; hh < NH; ++hh) ssum += __expf(raw[hh * 32 + ch] - m);
    da[b * CC + t] = __expf(raw[t] - m) / ssum;
}

// ---------------- combine: conv + fa + gating (sliding window) -------------
template<int KS>
__device__ __forceinline__ void comb_body(
    uint* vt, int qq,
    const float* __restrict__ qkv, const float* __restrict__ da,
    const uint* __restrict__ wtab, const float* __restrict__ btab,
    ushort* __restrict__ out)
{
    constexpr int R = KS / 2;
    constexpr int TR = KS + 1;
    constexpr int WCOLS = 7 + 2 * R;
    const int hx = blockIdx.x & 1;
    const int y0 = blockIdx.y * 2, b = blockIdx.z;
    const int x0 = hx * 28;
    const int t = threadIdx.x;
    const int c0 = qq * 64;
    const int p = t & 31;

    // packed weights: coalesced broadcast loads from the precomputed table
    uint wpk[KS * KS];
    #pragma unroll
    for (int i = 0; i < KS * KS; ++i) wpk[i] = wtab[(qq * 49 + i) * 32 + p];
    const float2 bb = *(const float2*)(btab + (qq * 32 + p) * 2);

    // stage TR rows x 34 cols, one bf16-pair per lane per position (bank = p)
    for (int pos = t >> 5; pos < TR * 34; pos += 8) {
        int row = pos / 34, col = pos - row * 34;
        int gy = y0 + row - R, gx = x0 + col - 3;
        float2 v = {0.f, 0.f};
        if ((unsigned)gy < 56u && (unsigned)gx < 56u)
            v = *(const float2*)(qkv + ((size_t)b * NN + gy * 56 + gx) * 768 + 512 + c0 + 2 * p);
        vt[pos * 32 + p] = pk2(v.x, v.y);
    }
    __syncthreads();

    const int rseg = t >> 5;
    const int r = rseg >> 2, sg = rseg & 3;
    float accA[7], accB[7];
    #pragma unroll
    for (int k = 0; k < 7; ++k) { accA[k] = bb.x; accB[k] = bb.y; }

    #pragma unroll
    for (int dy = 0; dy < KS; ++dy) {
        const int rowbase = (r + dy) * 34 * 32;
        float fA[WCOLS], fB[WCOLS];
        #pragma unroll
        for (int u = 0; u < WCOLS; ++u) {
            uint vv = vt[rowbase + (sg * 7 + 3 - R + u) * 32 + p];
            fA[u] = unlo(vv); fB[u] = unhi(vv);
        }
        #pragma unroll
        for (int dx = 0; dx < KS; ++dx) {
            uint wv = wpk[dy * KS + dx];
            float wl = unlo(wv), wh = unhi(wv);
            #pragma unroll
            for (int k = 0; k < 7; ++k) {
                accA[k] = fmaf(fA[dx + k], wl, accA[k]);
                accB[k] = fmaf(fB[dx + k], wh, accB[k]);
            }
        }
    }

    const int cA = c0 + 2 * p;
    const float2 da2 = *(const float2*)(da + b * CC + cA);
    const int ytok = y0 + r;
    #pragma unroll
    for (int k = 0; k < 7; ++k) {
        size_t tok = (size_t)b * NN + ytok * 56 + x0 + sg * 7 + k;
        float2 q2 = *(const float2*)(qkv + tok * 768 + cA);
        float2 fa2 = *(const float2*)(qkv + tok * 768 + 256 + cA);
        ushort2 o = { f2bf(da2.x * (SCALE * fa2.x + q2.x * accA[k])),
                      f2bf(da2.y * (SCALE * fa2.y + q2.y * accB[k])) };
        *(ushort2*)(out + tok * CC + cA) = o;
    }
}

__global__ __launch_bounds__(256) void combine_kernel(
    const float* __restrict__ qkv, const float* __restrict__ da,
    const uint* __restrict__ wtab, const float* __restrict__ btab,
    ushort* __restrict__ out)
{
    __shared__ uint vt[8 * 34 * 32];
    switch (blockIdx.x >> 1) {
    case 0:  comb_body<3>(vt, 0, qkv, da, wtab, btab, out); break;
    case 1:  comb_body<5>(vt, 1, qkv, da, wtab, btab, out); break;
    case 2:  comb_body<7>(vt, 2, qkv, da, wtab, btab, out); break;
    default: comb_body<7>(vt, 3, qkv, da, wtab, btab, out); break;
    }
}

// ---------------- launch ----------------
extern "C" void kernel_launch(void* const* d_in, const int* in_sizes, int n_in,
                              void* d_out, int out_size, void* d_ws, size_t ws_size,
                              hipStream_t stream)
{
    const float* x       = (const float*)d_in[0];
    const float* dlab    = (const float*)d_in[1];
    const float* cpe_w   = (const float*)d_in[2];
    const float* cpe_b   = (const float*)d_in[3];
    const float* ln1_g   = (const float*)d_in[4];
    const float* ln1_b   = (const float*)d_in[5];
    const float* qkv_w   = (const float*)d_in[6];
    const float* proj_w  = (const float*)d_in[7];
    const float* proj_b  = (const float*)d_in[8];
    const float* dl_w1   = (const float*)d_in[9];
    const float* dl_b1   = (const float*)d_in[10];
    const float* dl_w2   = (const float*)d_in[11];
    const float* dl_b2   = (const float*)d_in[12];
    const float* crpe_w3 = (const float*)d_in[13];
    const float* crpe_b3 = (const float*)d_in[14];
    const float* crpe_w5 = (const float*)d_in[15];
    const float* crpe_b5 = (const float*)d_in[16];
    const float* crpe_w7 = (const float*)d_in[17];
    const float* crpe_b7 = (const float*)d_in[18];
    const float* ln2_g   = (const float*)d_in[19];
    const float* ln2_b   = (const float*)d_in[20];
    const float* fc1_w   = (const float*)d_in[21];
    const float* fc1_b   = (const float*)d_in[22];
    const float* fc2_w   = (const float*)d_in[23];
    const float* fc2_b   = (const float*)d_in[24];
    const int*   dptr    = (const int*)d_in[27];

    float* out = (float*)d_out;
    char* W = (char*)d_ws;
    size_t off = 0;
    float* x1 = (float*)(W + off);          off += (size_t)NT * CC * 4;   // f32 [NT,C]
    float* qkv = (float*)(W + off);                                        // f32 [NT,768]
    ushort* hidden = (ushort*)qkv;                                         // overlay: bf16 [NT,1024]
    off += (size_t)NT * 768 * 4;
    ushort* actbf = (ushort*)(W + off);     off += (size_t)NT * CC * 2;   // bf16 [NT,C]
    // overlay: kv partials live only between qkv-GEMM and fa, while actbf is dead
    float* partial = (float*)actbf;                    // 16*65536 f32 = 4 MB
    float* psum = partial + (size_t)16 * 65536;        // 32768 f32
    float* kvb = (float*)(W + off);         off += (size_t)65536 * 4;
    float* dab = (float*)(W + off);         off += (size_t)BB * CC * 4;
    float* pmax = (float*)(W + off);        off += (size_t)BB * 32 * CC * 4;
    float* cmax = (float*)(W + off);        off += (size_t)BB * CC * 4;
    ushort* wq  = (ushort*)(W + off);       off += (size_t)768 * 256 * 2;
    ushort* wp  = (ushort*)(W + off);       off += (size_t)256 * 256 * 2;
    ushort* w1t = (ushort*)(W + off);       off += (size_t)1024 * 256 * 2;
    ushort* w2t = (ushort*)(W + off);       off += (size_t)256 * 1024 * 2;
    uint* wcomb = (uint*)(W + off);         off += (size_t)4 * 49 * 32 * 4;
    float* bcomb = (float*)(W + off);       off += (size_t)4 * 32 * 2 * 4;
    uint* wcpe = (uint*)(W + off);          off += (size_t)4 * 9 * 32 * 4;
    float* bcpe = (float*)(W + off);        off += (size_t)4 * 32 * 2 * 4;

    // 0. weight packing / transpose (tiny, one-time per launch)
    hipLaunchKernelGGL(wpack_kernel, dim3(4), dim3(256), 0, stream,
                       crpe_w3, crpe_b3, crpe_w5, crpe_b5, crpe_w7, crpe_b7, wcomb, bcomb);
    hipLaunchKernelGGL(cpack_kernel, dim3(4), dim3(256), 0, stream, cpe_w, cpe_b, wcpe, bcpe);
    hipLaunchKernelGGL(wtrans_kernel, dim3(768 / 32, 256 / 32), dim3(256), 0, stream, qkv_w, wq, 256, 768);
    hipLaunchKernelGGL(wtrans_kernel, dim3(256 / 32, 256 / 32), dim3(256), 0, stream, proj_w, wp, 256, 256);
    hipLaunchKernelGGL(wtrans_kernel, dim3(1024 / 32, 256 / 32), dim3(256), 0, stream, fc1_w, w1t, 256, 1024);
    hipLaunchKernelGGL(wtrans_kernel, dim3(256 / 32, 1024 / 32), dim3(256), 0, stream, fc2_w, w2t, 1024, 256);
    // 1. CPE -> x1 (f32)
    hipLaunchKernelGGL(cpe_kernel, dim3(8, 28, 8), dim3(256), 0, stream, x, wcpe, bcpe, x1);
    // 2. domain gating
    hipLaunchKernelGGL(da_kernel, dim3(BB), dim3(256), 0, stream,
                       dlab, dl_w1, dl_b1, dl_w2, dl_b2, dab);
    // 3. LN1 -> actbf (bf16)
    hipLaunchKernelGGL(ln_kernel, dim3(NT / 4), dim3(256), 0, stream,
                       x1, ln1_g, ln1_b, dptr, actbf);
    // 4. qkv GEMM: [NT,256]bf16 @ [768,256]^T -> qkv f32
    hipLaunchKernelGGL(gemm_mfma<0>, dim3(768 / 128, NT / 128), dim3(256), 0, stream,
                       actbf, wq, nullptr, nullptr, (void*)qkv, NT, 768, 256);
    // 5. k column max (chunked) + reduce
    hipLaunchKernelGGL(kmax1_kernel, dim3(32, 8), dim3(256), 0, stream, qkv, pmax);
    hipLaunchKernelGGL(kmax2_kernel, dim3(8), dim3(256), 0, stream, pmax, cmax);
    // 6. kv partial sums + normalize
    hipLaunchKernelGGL(kvacc_kernel, dim3(16, 8, 8), dim3(256), 0, stream,
                       qkv, cmax, partial, psum);
    hipLaunchKernelGGL(kvnorm_kernel, dim3(256), dim3(256), 0, stream,
                       partial, psum, kvb);
    // 7. fa = q @ kv -> written into qkv's k-slot (k is dead now)
    hipLaunchKernelGGL(fa_kernel, dim3(7, 8, 8), dim3(256), 0, stream, qkv, kvb);
    // 8. combine (conv + fa + gating) -> actbf (bf16)
    hipLaunchKernelGGL(combine_kernel, dim3(8, 28, 8), dim3(256), 0, stream,
                       qkv, dab, wcomb, bcomb, actbf);
    // 9. proj GEMM + bias + residual(x1) -> d_out f32
    hipLaunchKernelGGL(gemm_mfma<3>, dim3(256 / 128, NT / 128), dim3(256), 0, stream,
                       actbf, wp, proj_b, x1, (void*)out, NT, 256, 256);
    // 10. LN2 -> actbf (bf16)
    hipLaunchKernelGGL(ln_kernel, dim3(NT / 4), dim3(256), 0, stream,
                       out, ln2_g, ln2_b, dptr, actbf);
    // 11. fc1 + gelu -> hidden (bf16)
    hipLaunchKernelGGL(gemm_mfma<2>, dim3(1024 / 128, NT / 128), dim3(256), 0, stream,
                       actbf, w1t, fc1_b, nullptr, (void*)hidden, NT, 1024, 256);
    // 12. fc2 + bias + residual(d_out) -> d_out f32
    hipLaunchKernelGGL(gemm_mfma<3>, dim3(256 / 128, NT / 128), dim3(256), 0, stream,
                       hidden, w2t, fc2_b, out, (void*)out, NT, 256, 1024);
}

// Round 7
// 396.570 us; speedup vs baseline: 1.1071x; 1.0746x over previous
//
#include <hip/hip_runtime.h>
#include <hip/hip_bf16.h>
#include <math.h>

// Problem constants (fixed by setup_inputs)
#define BB 8
#define HH 56
#define WW 56
#define NN (HH*WW)          // 3136
#define CC 256
#define NH 8
#define NT (BB*NN)          // 25088
#define HID 128
#define MH 1024
#define SCALE 0.17677669529663687f   // 32^-0.5

typedef __attribute__((ext_vector_type(8))) short bf16x8;
typedef __attribute__((ext_vector_type(4))) float f32x4;

__device__ __forceinline__ ushort f2bf(float f) {
    __hip_bfloat16 h = __float2bfloat16(f);
    return *(ushort*)&h;
}
__device__ __forceinline__ float bf2f(ushort u) {
    union { unsigned int i; float f; } x; x.i = ((unsigned int)u) << 16; return x.f;
}
__device__ __forceinline__ uint pk2(float lo, float hi) {
    return ((uint)f2bf(hi) << 16) | (uint)f2bf(lo);
}
__device__ __forceinline__ float unlo(uint u) { return __uint_as_float(u << 16); }
__device__ __forceinline__ float unhi(uint u) { return __uint_as_float(u & 0xFFFF0000u); }

__device__ __forceinline__ void gload16(const void* g, void* s) {
    __builtin_amdgcn_global_load_lds(
        (const __attribute__((address_space(1))) void*)g,
        (__attribute__((address_space(3))) void*)s, 16, 0, 0);
}

// ---------------- weight transpose + f32->bf16 + epilogue permutation ------
// w[K][N] -> wt[perm(N)][K]; within each 64-col block, permuted position
// p = j*16+lrow holds original column 4*lrow+j, so MFMA lane lrow's 4
// j-fragments are 4 CONTIGUOUS output columns (vectorized C-store).
__global__ __launch_bounds__(256) void wtrans_kernel(
    const float* __restrict__ w, ushort* __restrict__ wt, int K, int N)
{
    __shared__ float tile[32][33];
    const int t = threadIdx.x;
    const int col = t & 31, rw = t >> 5;
    const int k0 = blockIdx.y * 32, n0 = blockIdx.x * 32;
    #pragma unroll
    for (int i = rw; i < 32; i += 8)
        tile[i][col] = w[(size_t)(k0 + i) * N + n0 + col];
    __syncthreads();
    #pragma unroll
    for (int i = rw; i < 32; i += 8) {
        int n = n0 + i;
        int nl = n & 63;
        int np = (n & ~63) | ((nl & 3) * 16 + (nl >> 2));
        wt[(size_t)np * K + k0 + col] = f2bf(tile[col][i]);
    }
}

// ---------------- pack CRPE weights: [qq][49][32] bf16-pairs ----------------
__global__ __launch_bounds__(256) void wpack_kernel(
    const float* __restrict__ w3, const float* __restrict__ b3,
    const float* __restrict__ w5, const float* __restrict__ b5,
    const float* __restrict__ w7, const float* __restrict__ b7,
    uint* __restrict__ wt, float* __restrict__ bt)
{
    const int qq = blockIdx.x;
    const int KSQ = (qq == 0) ? 3 : (qq == 1) ? 5 : 7;
    for (int idx = threadIdx.x; idx < 49 * 32; idx += 256) {
        int tap = idx >> 5, p = idx & 31;
        int cA = qq * 64 + 2 * p;
        float lo = 0.f, hi = 0.f;
        if (tap < KSQ * KSQ) {
            int dy = tap / KSQ, dx = tap - dy * KSQ;
            const float* wb; int kslo;
            if (cA < 64)       { wb = w3 + cA * 9;          kslo = 3; }
            else if (cA < 160) { wb = w5 + (cA - 64) * 25;  kslo = 5; }
            else               { wb = w7 + (cA - 160) * 49; kslo = 7; }
            int offp = KSQ / 2 - kslo / 2;
            int sy = dy - offp, sx = dx - offp;
            if (sy >= 0 && sy < kslo && sx >= 0 && sx < kslo) {
                lo = wb[sy * kslo + sx];
                hi = wb[kslo * kslo + sy * kslo + sx];
            }
        }
        wt[(qq * 49 + tap) * 32 + p] = pk2(lo, hi);
    }
    if (threadIdx.x < 32) {
        int p = threadIdx.x, cA = qq * 64 + 2 * p;
        float blo, bhi;
        if (cA < 64)       { blo = b3[cA];       bhi = b3[cA + 1]; }
        else if (cA < 160) { blo = b5[cA - 64];  bhi = b5[cA - 63]; }
        else               { blo = b7[cA - 160]; bhi = b7[cA - 159]; }
        bt[(qq * 32 + p) * 2]     = blo;
        bt[(qq * 32 + p) * 2 + 1] = bhi;
    }
}

// ---------------- pack CPE weights: [qq][9][32] bf16-pairs ----------------
__global__ __launch_bounds__(256) void cpack_kernel(
    const float* __restrict__ w, const float* __restrict__ bias,
    uint* __restrict__ wt, float* __restrict__ bt)
{
    const int qq = blockIdx.x;
    for (int idx = threadIdx.x; idx < 9 * 32; idx += 256) {
        int tap = idx >> 5, p = idx & 31;
        int cA = qq * 64 + 2 * p;
        wt[(qq * 9 + tap) * 32 + p] = pk2(w[cA * 9 + tap], w[(cA + 1) * 9 + tap]);
    }
    if (threadIdx.x < 32) {
        int p = threadIdx.x, cA = qq * 64 + 2 * p;
        bt[(qq * 32 + p) * 2]     = bias[cA];
        bt[(qq * 32 + p) * 2 + 1] = bias[cA + 1];
    }
}

// ---------------- CPE: depthwise 3x3 + bias + residual (sliding window) ----
__global__ __launch_bounds__(256) void cpe_kernel(
    const float* __restrict__ x, const uint* __restrict__ wtab,
    const float* __restrict__ btab, float* __restrict__ out)
{
    __shared__ uint vt[4 * 34 * 32];
    const int qq = blockIdx.x >> 1, hx = blockIdx.x & 1;
    const int y0 = blockIdx.y * 2, b = blockIdx.z;
    const int x0 = hx * 28;
    const int t = threadIdx.x;
    const int c0 = qq * 64;
    const int p = t & 31;

    uint wpk[9];
    #pragma unroll
    for (int i = 0; i < 9; ++i) wpk[i] = wtab[(qq * 9 + i) * 32 + p];
    const float2 bb = *(const float2*)(btab + (qq * 32 + p) * 2);

    for (int pos = t >> 5; pos < 4 * 34; pos += 8) {
        int row = pos / 34, col = pos - row * 34;
        int gy = y0 + row - 1, gx = x0 + col - 3;
        float2 v = {0.f, 0.f};
        if ((unsigned)gy < 56u && (unsigned)gx < 56u)
            v = *(const float2*)(x + ((size_t)b * NN + gy * 56 + gx) * CC + c0 + 2 * p);
        vt[pos * 32 + p] = pk2(v.x, v.y);
    }
    __syncthreads();

    const int rseg = t >> 5;
    const int r = rseg >> 2, sg = rseg & 3;
    float accA[7], accB[7];
    #pragma unroll
    for (int k = 0; k < 7; ++k) { accA[k] = bb.x; accB[k] = bb.y; }

    #pragma unroll
    for (int dy = 0; dy < 3; ++dy) {
        const int rowbase = (r + dy) * 34 * 32;
        float fA[9], fB[9];
        #pragma unroll
        for (int u = 0; u < 9; ++u) {
            uint vv = vt[rowbase + (sg * 7 + 2 + u) * 32 + p];
            fA[u] = unlo(vv); fB[u] = unhi(vv);
        }
        #pragma unroll
        for (int dx = 0; dx < 3; ++dx) {
            uint wv = wpk[dy * 3 + dx];
            float wl = unlo(wv), wh = unhi(wv);
            #pragma unroll
            for (int k = 0; k < 7; ++k) {
                accA[k] = fmaf(fA[dx + k], wl, accA[k]);
                accB[k] = fmaf(fB[dx + k], wh, accB[k]);
            }
        }
    }

    const int cA = c0 + 2 * p;
    const int ytok = y0 + r;
    #pragma unroll
    for (int k = 0; k < 7; ++k) {
        size_t tok = (size_t)b * NN + ytok * 56 + x0 + sg * 7 + k;
        float2 res = *(const float2*)(x + tok * CC + cA);
        float2 o = { accA[k] + res.x, accB[k] + res.y };
        *(float2*)(out + tok * CC + cA) = o;
    }
}

// ---------------- LayerNorm over C=256, wave-per-row, bf16 out ----------------
__global__ __launch_bounds__(256) void ln_kernel(
    const float* __restrict__ src, const float* __restrict__ g_all,
    const float* __restrict__ b_all, const int* __restrict__ dptr,
    ushort* __restrict__ dst)
{
    const int wid = threadIdx.x >> 6, lane = threadIdx.x & 63;
    const int row = blockIdx.x * 4 + wid;
    const int d = *dptr;
    const float* g = g_all + d * CC;
    const float* be = b_all + d * CC;
    const float* p = src + (size_t)row * CC;
    float4 v = *(const float4*)(p + lane * 4);
    float s = v.x + v.y + v.z + v.w;
    float sq = v.x*v.x + v.y*v.y + v.z*v.z + v.w*v.w;
    #pragma unroll
    for (int off = 1; off < 64; off <<= 1) {
        s  += __shfl_xor(s, off);
        sq += __shfl_xor(sq, off);
    }
    const float mean = s * (1.f / CC);
    const float var = sq * (1.f / CC) - mean * mean;
    const float rs = rsqrtf(var + 1e-5f);
    float4 g4 = *(const float4*)(g + lane * 4);
    float4 b4 = *(const float4*)(be + lane * 4);
    ushort4 o4;
    o4.x = f2bf((v.x - mean) * rs * g4.x + b4.x);
    o4.y = f2bf((v.y - mean) * rs * g4.y + b4.y);
    o4.z = f2bf((v.z - mean) * rs * g4.z + b4.z);
    o4.w = f2bf((v.w - mean) * rs * g4.w + b4.w);
    *(ushort4*)(dst + (size_t)row * CC + lane * 4) = o4;
}

// ---------------- bf16 MFMA GEMM: C = A[M][K] @ Bt_perm[N][K]^T ----------------
// EPI: 1 = bf16 raw, 2 = bf16 bias+gelu, 3 = f32 bias+residual
// B pre-permuted (wtrans) -> lane owns 4 contiguous out cols -> vector stores.
// 1D grid with bijective XCD swizzle (all bn of one bm land on same XCD L2).
template<int EPI>
__global__ __launch_bounds__(256) void gemm_mfma(
    const ushort* __restrict__ A, const ushort* __restrict__ Bt,
    const float* __restrict__ bias, const float* __restrict__ res,
    void* __restrict__ Cv, int M, int N, int K, int nbn, int nwg)
{
    __shared__ __align__(16) ushort Als[128 * 32];
    __shared__ __align__(16) ushort Bls[128 * 32];
    const int t = threadIdx.x;
    // m204 bijective XCD swizzle
    const int lin = blockIdx.x;
    const int q8 = nwg >> 3, r8 = nwg & 7;
    const int xcd = lin & 7, i8 = lin >> 3;
    const int wgid = (xcd < r8 ? xcd * (q8 + 1) : r8 * (q8 + 1) + (xcd - r8) * q8) + i8;
    const int bm = wgid / nbn, bn = wgid - bm * nbn;
    const int brow = bm * 128, bcol = bn * 128;
    const int lane = t & 63, w = t >> 6;
    const int wr = w >> 1, wc = w & 1;
    const int lrow = lane & 15, lko = (lane >> 4) * 8;

    const ushort* gA0 = A + (size_t)(brow + (t >> 2)) * K + (t & 3) * 8;
    const ushort* gA1 = gA0 + (size_t)64 * K;
    const ushort* gB0 = Bt + (size_t)(bcol + (t >> 2)) * K + (t & 3) * 8;
    const ushort* gB1 = gB0 + (size_t)64 * K;
    ushort* lA0 = &Als[t * 8];  ushort* lA1 = &Als[64 * 32 + t * 8];
    ushort* lB0 = &Bls[t * 8];  ushort* lB1 = &Bls[64 * 32 + t * 8];

    f32x4 acc[4][4] = {};

    for (int kt = 0; kt < K; kt += 32) {
        gload16(gA0 + kt, lA0);
        gload16(gA1 + kt, lA1);
        gload16(gB0 + kt, lB0);
        gload16(gB1 + kt, lB1);
        __syncthreads();
        bf16x8 af[4], bfr[4];
        #pragma unroll
        for (int i = 0; i < 4; ++i)
            af[i] = *(const bf16x8*)&Als[(wr * 64 + i * 16 + lrow) * 32 + lko];
        #pragma unroll
        for (int j = 0; j < 4; ++j)
            bfr[j] = *(const bf16x8*)&Bls[(wc * 64 + j * 16 + lrow) * 32 + lko];
        #pragma unroll
        for (int i = 0; i < 4; ++i)
            #pragma unroll
            for (int j = 0; j < 4; ++j)
                acc[i][j] = __builtin_amdgcn_mfma_f32_16x16x32_bf16(
                    af[i], bfr[j], acc[i][j], 0, 0, 0);
        __syncthreads();
    }

    float* Cf = (float*)Cv;
    ushort* Ch = (ushort*)Cv;
    const int col0 = bcol + wc * 64 + 4 * lrow;   // 4 contiguous original cols
    float bias4[4] = {0.f, 0.f, 0.f, 0.f};
    if (EPI >= 2) {
        float4 bv = *(const float4*)(bias + col0);
        bias4[0] = bv.x; bias4[1] = bv.y; bias4[2] = bv.z; bias4[3] = bv.w;
    }
    #pragma unroll
    for (int i = 0; i < 4; ++i) {
        #pragma unroll
        for (int r = 0; r < 4; ++r) {
            const int row = brow + wr * 64 + i * 16 + (lane >> 4) * 4 + r;
            size_t off = (size_t)row * N + col0;
            float o[4];
            #pragma unroll
            for (int j = 0; j < 4; ++j) o[j] = acc[i][j][r] + bias4[j];
            if (EPI == 2) {
                #pragma unroll
                for (int j = 0; j < 4; ++j)
                    o[j] = 0.5f * o[j] * (1.f + erff(o[j] * 0.70710678118654752f));
                ushort4 st = { f2bf(o[0]), f2bf(o[1]), f2bf(o[2]), f2bf(o[3]) };
                *(ushort4*)(Ch + off) = st;
            } else if (EPI == 1) {
                ushort4 st = { f2bf(o[0]), f2bf(o[1]), f2bf(o[2]), f2bf(o[3]) };
                *(ushort4*)(Ch + off) = st;
            } else {
                float4 rv = *(const float4*)(res + off);
                float4 st = { o[0] + rv.x, o[1] + rv.y, o[2] + rv.z, o[3] + rv.w };
                *(float4*)(Cf + off) = st;
            }
        }
    }
}

// ---------------- k softmax: per-chunk column max + reduce (bf16 qkv) -------
__global__ __launch_bounds__(256) void kmax1_kernel(
    const ushort* __restrict__ qkv, float* __restrict__ pmax)
{
    const int chunk = blockIdx.x, b = blockIdx.y, c = threadIdx.x;
    const ushort* kb = qkv + (size_t)(b * NN + chunk * 98) * 768 + 256 + c;
    float m = -3.4e38f;
    for (int i = 0; i < 98; ++i) m = fmaxf(m, bf2f(kb[(size_t)i * 768]));
    pmax[(b * 32 + chunk) * CC + c] = m;
}

__global__ __launch_bounds__(256) void kmax2_kernel(
    const float* __restrict__ pmax, float* __restrict__ cmax)
{
    const int b = blockIdx.x, c = threadIdx.x;
    float m = -3.4e38f;
    #pragma unroll
    for (int i = 0; i < 32; ++i) m = fmaxf(m, pmax[(b * 32 + i) * CC + c]);
    cmax[b * CC + c] = m;
}

// ---------------- kv partial: per-chunk exp-weighted sums (bf16 qkv) --------
__global__ __launch_bounds__(256) void kvacc_kernel(
    const ushort* __restrict__ qkv, const float* __restrict__ cmax,
    float* __restrict__ partial, float* __restrict__ psum)
{
    const int chunk = blockIdx.x, h = blockIdx.y, b = blockIdx.z;
    const int t = threadIdx.x;
    const int ck = t & 31, g = t >> 5;
    const int n0 = chunk * 196;
    const ushort* kb = qkv + (size_t)(b * NN + n0) * 768 + 256 + h * 32 + ck;
    const ushort* vb = qkv + (size_t)(b * NN + n0) * 768 + 512 + h * 32 + g * 4;
    const float cm = cmax[b * CC + h * 32 + ck];
    float a0 = 0.f, a1 = 0.f, a2 = 0.f, a3 = 0.f, s = 0.f;
    for (int i = 0; i < 196; ++i) {
        float e = __expf(bf2f(kb[(size_t)i * 768]) - cm);
        ushort4 v4 = *(const ushort4*)(vb + (size_t)i * 768);
        a0 += e * bf2f(v4.x); a1 += e * bf2f(v4.y);
        a2 += e * bf2f(v4.z); a3 += e * bf2f(v4.w);
        s += e;
    }
    float4 o = {a0, a1, a2, a3};
    *(float4*)(partial + ((((size_t)chunk * 8 + b) * 8 + h) * 32 + ck) * 32 + g * 4) = o;
    if (g == 0) psum[((chunk * 8 + b) * 8 + h) * 32 + ck] = s;
}

__global__ __launch_bounds__(256) void kvnorm_kernel(
    const float* __restrict__ partial, const float* __restrict__ psum,
    float* __restrict__ kv)
{
    const int idx = blockIdx.x * 256 + threadIdx.x;   // [b][h][ck][cv]
    const int ckidx = idx >> 5;
    float sum = 0.f, cs = 0.f;
    #pragma unroll
    for (int ch = 0; ch < 16; ++ch) {
        sum += partial[(size_t)ch * 65536 + idx];
        cs  += psum[ch * 2048 + ckidx];
    }
    kv[idx] = sum / cs;
}

// ---------------- fa GEMM: fa[b,h] = q[b,:,h] @ kv[b,h]  (into k-slot) ------
// B fragment permuted so lane lr owns cols {2lr, 2lr+1} -> paired uint store.
__global__ __launch_bounds__(256) void fa_kernel(
    ushort* __restrict__ qkv, const float* __restrict__ kvb)
{
    const int mt = blockIdx.x, h = blockIdx.y, b = blockIdx.z;
    const int t = threadIdx.x;
    const int lane = t & 63, wv = t >> 6;
    const int row0 = mt * 448 + wv * 112;
    const int lr = lane & 15, lk = (lane >> 4) * 8;

    bf16x8 bfr[2];
    #pragma unroll
    for (int jj = 0; jj < 2; ++jj)
        #pragma unroll
        for (int e = 0; e < 8; ++e)
            bfr[jj][e] = (short)f2bf(kvb[((size_t)(b * 8 + h) * 32 + lk + e) * 32 + 2 * lr + jj]);

    #pragma unroll
    for (int i = 0; i < 7; ++i) {
        size_t tok = (size_t)b * NN + row0 + i * 16 + lr;
        bf16x8 af = *(const bf16x8*)(qkv + tok * 768 + h * 32 + lk);
        f32x4 a0 = {0.f, 0.f, 0.f, 0.f}, a1 = {0.f, 0.f, 0.f, 0.f};
        a0 = __builtin_amdgcn_mfma_f32_16x16x32_bf16(af, bfr[0], a0, 0, 0, 0);
        a1 = __builtin_amdgcn_mfma_f32_16x16x32_bf16(af, bfr[1], a1, 0, 0, 0);
        #pragma unroll
        for (int r = 0; r < 4; ++r) {
            size_t trow = (size_t)b * NN + row0 + i * 16 + (lane >> 4) * 4 + r;
            *(uint*)(qkv + trow * 768 + 256 + h * 32 + 2 * lr) = pk2(a0[r], a1[r]);
        }
    }
}

// ---------------- domain gating ----------------
__global__ __launch_bounds__(256) void da_kernel(
    const float* __restrict__ dl, const float* __restrict__ w1,
    const float* __restrict__ b1, const float* __restrict__ w2,
    const float* __restrict__ b2, float* __restrict__ da)
{
    const int b = blockIdx.x, t = threadIdx.x;
    __shared__ float r[HID];
    __shared__ float raw[CC];
    if (t < HID) {
        float s = b1[t];
        #pragma unroll
        for (int k = 0; k < 4; ++k) s += dl[b * 4 + k] * w1[k * HID + t];
        r[t] = fmaxf(s, 0.f);
    }
    __syncthreads();
    float s = b2[t];
    for (int j = 0; j < HID; ++j) s += r[j] * w2[j * CC + t];
    raw[t] = s;
    __syncthreads();
    const int ch = t & 31;
    float m = -3.4e38f;
    #pragma unroll
    for (int hh = 0; hh < NH; ++hh) m = fmaxf(m, raw[hh * 32 + ch]);
    float ssum = 0.f;
    #pragma unroll
    for (int hh = 0; hh < NH; ++hh) ssum += __expf(raw[hh * 32 + ch] - m);
    da[b * CC + t] = __expf(raw[t] - m) / ssum;
}

// ---------------- combine: conv + fa + gating (sliding window, bf16 qkv) ----
template<int KS>
__device__ __forceinline__ void comb_body(
    uint* vt, int qq,
    const ushort* __restrict__ qkv, const float* __restrict__ da,
    const uint* __restrict__ wtab, const float* __restrict__ btab,
    ushort* __restrict__ out)
{
    constexpr int R = KS / 2;
    constexpr int TR = KS + 1;
    constexpr int WCOLS = 7 + 2 * R;
    const int hx = blockIdx.x & 1;
    const int y0 = blockIdx.y * 2, b = blockIdx.z;
    const int x0 = hx * 28;
    const int t = threadIdx.x;
    const int c0 = qq * 64;
    const int p = t & 31;

    uint wpk[KS * KS];
    #pragma unroll
    for (int i = 0; i < KS * KS; ++i) wpk[i] = wtab[(qq * 49 + i) * 32 + p];
    const float2 bb = *(const float2*)(btab + (qq * 32 + p) * 2);

    // stage: direct uint (bf16-pair) copy from global, bank = p
    for (int pos = t >> 5; pos < TR * 34; pos += 8) {
        int row = pos / 34, col = pos - row * 34;
        int gy = y0 + row - R, gx = x0 + col - 3;
        uint v = 0;
        if ((unsigned)gy < 56u && (unsigned)gx < 56u)
            v = *(const uint*)(qkv + ((size_t)b * NN + gy * 56 + gx) * 768 + 512 + c0 + 2 * p);
        vt[pos * 32 + p] = v;
    }
    __syncthreads();

    const int rseg = t >> 5;
    const int r = rseg >> 2, sg = rseg & 3;
    float accA[7], accB[7];
    #pragma unroll
    for (int k = 0; k < 7; ++k) { accA[k] = bb.x; accB[k] = bb.y; }

    #pragma unroll
    for (int dy = 0; dy < KS; ++dy) {
        const int rowbase = (r + dy) * 34 * 32;
        float fA[WCOLS], fB[WCOLS];
        #pragma unroll
        for (int u = 0; u < WCOLS; ++u) {
            uint vv = vt[rowbase + (sg * 7 + 3 - R + u) * 32 + p];
            fA[u] = unlo(vv); fB[u] = unhi(vv);
        }
        #pragma unroll
        for (int dx = 0; dx < KS; ++dx) {
            uint wv = wpk[dy * KS + dx];
            float wl = unlo(wv), wh = unhi(wv);
            #pragma unroll
            for (int k = 0; k < 7; ++k) {
                accA[k] = fmaf(fA[dx + k], wl, accA[k]);
                accB[k] = fmaf(fB[dx + k], wh, accB[k]);
            }
        }
    }

    const int cA = c0 + 2 * p;
    const float2 da2 = *(const float2*)(da + b * CC + cA);
    const int ytok = y0 + r;
    #pragma unroll
    for (int k = 0; k < 7; ++k) {
        size_t tok = (size_t)b * NN + ytok * 56 + x0 + sg * 7 + k;
        uint qw = *(const uint*)(qkv + tok * 768 + cA);
        uint fw = *(const uint*)(qkv + tok * 768 + 256 + cA);
        ushort2 o = { f2bf(da2.x * (SCALE * unlo(fw) + unlo(qw) * accA[k])),
                      f2bf(da2.y * (SCALE * unhi(fw) + unhi(qw) * accB[k])) };
        *(ushort2*)(out + tok * CC + cA) = o;
    }
}

__global__ __launch_bounds__(256) void combine_kernel(
    const ushort* __restrict__ qkv, const float* __restrict__ da,
    const uint* __restrict__ wtab, const float* __restrict__ btab,
    ushort* __restrict__ out)
{
    __shared__ uint vt[8 * 34 * 32];
    switch (blockIdx.x >> 1) {
    case 0:  comb_body<3>(vt, 0, qkv, da, wtab, btab, out); break;
    case 1:  comb_body<5>(vt, 1, qkv, da, wtab, btab, out); break;
    case 2:  comb_body<7>(vt, 2, qkv, da, wtab, btab, out); break;
    default: comb_body<7>(vt, 3, qkv, da, wtab, btab, out); break;
    }
}

// ---------------- launch ----------------
extern "C" void kernel_launch(void* const* d_in, const int* in_sizes, int n_in,
                              void* d_out, int out_size, void* d_ws, size_t ws_size,
                              hipStream_t stream)
{
    const float* x       = (const float*)d_in[0];
    const float* dlab    = (const float*)d_in[1];
    const float* cpe_w   = (const float*)d_in[2];
    const float* cpe_b   = (const float*)d_in[3];
    const float* ln1_g   = (const float*)d_in[4];
    const float* ln1_b   = (const float*)d_in[5];
    const float* qkv_w   = (const float*)d_in[6];
    const float* proj_w  = (const float*)d_in[7];
    const float* proj_b  = (const float*)d_in[8];
    const float* dl_w1   = (const float*)d_in[9];
    const float* dl_b1   = (const float*)d_in[10];
    const float* dl_w2   = (const float*)d_in[11];
    const float* dl_b2   = (const float*)d_in[12];
    const float* crpe_w3 = (const float*)d_in[13];
    const float* crpe_b3 = (const float*)d_in[14];
    const float* crpe_w5 = (const float*)d_in[15];
    const float* crpe_b5 = (const float*)d_in[16];
    const float* crpe_w7 = (const float*)d_in[17];
    const float* crpe_b7 = (const float*)d_in[18];
    const float* ln2_g   = (const float*)d_in[19];
    const float* ln2_b   = (const float*)d_in[20];
    const float* fc1_w   = (const float*)d_in[21];
    const float* fc1_b   = (const float*)d_in[22];
    const float* fc2_w   = (const float*)d_in[23];
    const float* fc2_b   = (const float*)d_in[24];
    const int*   dptr    = (const int*)d_in[27];

    float* out = (float*)d_out;
    char* W = (char*)d_ws;
    size_t off = 0;
    float* x1 = (float*)(W + off);          off += (size_t)NT * CC * 4;    // f32 [NT,C]
    // union region: qkv bf16 [NT,768] (38.6MB) / mlp hidden bf16 [NT,1024] (51.4MB)
    ushort* qkvb = (ushort*)(W + off);
    ushort* hidden = (ushort*)(W + off);    off += (size_t)NT * MH * 2;
    ushort* actbf = (ushort*)(W + off);     off += (size_t)NT * CC * 2;    // bf16 [NT,C]
    // overlay: kv partials live only between qkv-GEMM and fa, while actbf is dead
    float* partial = (float*)actbf;                    // 16*65536 f32 = 4 MB
    float* psum = partial + (size_t)16 * 65536;        // 32768 f32
    float* kvb = (float*)(W + off);         off += (size_t)65536 * 4;
    float* dab = (float*)(W + off);         off += (size_t)BB * CC * 4;
    float* pmax = (float*)(W + off);        off += (size_t)BB * 32 * CC * 4;
    float* cmax = (float*)(W + off);        off += (size_t)BB * CC * 4;
    ushort* wq  = (ushort*)(W + off);       off += (size_t)768 * 256 * 2;
    ushort* wp  = (ushort*)(W + off);       off += (size_t)256 * 256 * 2;
    ushort* w1t = (ushort*)(W + off);       off += (size_t)1024 * 256 * 2;
    ushort* w2t = (ushort*)(W + off);       off += (size_t)256 * 1024 * 2;
    uint* wcomb = (uint*)(W + off);         off += (size_t)4 * 49 * 32 * 4;
    float* bcomb = (float*)(W + off);       off += (size_t)4 * 32 * 2 * 4;
    uint* wcpe = (uint*)(W + off);          off += (size_t)4 * 9 * 32 * 4;
    float* bcpe = (float*)(W + off);        off += (size_t)4 * 32 * 2 * 4;

    // 0. weight packing / transpose (tiny, one-time per launch)
    hipLaunchKernelGGL(wpack_kernel, dim3(4), dim3(256), 0, stream,
                       crpe_w3, crpe_b3, crpe_w5, crpe_b5, crpe_w7, crpe_b7, wcomb, bcomb);
    hipLaunchKernelGGL(cpack_kernel, dim3(4), dim3(256), 0, stream, cpe_w, cpe_b, wcpe, bcpe);
    hipLaunchKernelGGL(wtrans_kernel, dim3(768 / 32, 256 / 32), dim3(256), 0, stream, qkv_w, wq, 256, 768);
    hipLaunchKernelGGL(wtrans_kernel, dim3(256 / 32, 256 / 32), dim3(256), 0, stream, proj_w, wp, 256, 256);
    hipLaunchKernelGGL(wtrans_kernel, dim3(1024 / 32, 256 / 32), dim3(256), 0, stream, fc1_w, w1t, 256, 1024);
    hipLaunchKernelGGL(wtrans_kernel, dim3(256 / 32, 1024 / 32), dim3(256), 0, stream, fc2_w, w2t, 1024, 256);
    // 1. CPE -> x1 (f32)
    hipLaunchKernelGGL(cpe_kernel, dim3(8, 28, 8), dim3(256), 0, stream, x, wcpe, bcpe, x1);
    // 2. domain gating
    hipLaunchKernelGGL(da_kernel, dim3(BB), dim3(256), 0, stream,
                       dlab, dl_w1, dl_b1, dl_w2, dl_b2, dab);
    // 3. LN1 -> actbf (bf16)
    hipLaunchKernelGGL(ln_kernel, dim3(NT / 4), dim3(256), 0, stream,
                       x1, ln1_g, ln1_b, dptr, actbf);
    // 4. qkv GEMM: [NT,256]bf16 @ [768,256]^T -> qkvb bf16
    hipLaunchKernelGGL(gemm_mfma<1>, dim3(196 * 6), dim3(256), 0, stream,
                       actbf, wq, nullptr, nullptr, (void*)qkvb, NT, 768, 256, 6, 196 * 6);
    // 5. k column max (chunked) + reduce
    hipLaunchKernelGGL(kmax1_kernel, dim3(32, 8), dim3(256), 0, stream, qkvb, pmax);
    hipLaunchKernelGGL(kmax2_kernel, dim3(8), dim3(256), 0, stream, pmax, cmax);
    // 6. kv partial sums + normalize
    hipLaunchKernelGGL(kvacc_kernel, dim3(16, 8, 8), dim3(256), 0, stream,
                       qkvb, cmax, partial, psum);
    hipLaunchKernelGGL(kvnorm_kernel, dim3(256), dim3(256), 0, stream,
                       partial, psum, kvb);
    // 7. fa = q @ kv -> written into qkvb's k-slot (k is dead now)
    hipLaunchKernelGGL(fa_kernel, dim3(7, 8, 8), dim3(256), 0, stream, qkvb, kvb);
    // 8. combine (conv + fa + gating) -> actbf (bf16)
    hipLaunchKernelGGL(combine_kernel, dim3(8, 28, 8), dim3(256), 0, stream,
                       qkvb, dab, wcomb, bcomb, actbf);
    // 9. proj GEMM + bias + residual(x1) -> d_out f32
    hipLaunchKernelGGL(gemm_mfma<3>, dim3(196 * 2), dim3(256), 0, stream,
                       actbf, wp, proj_b, x1, (void*)out, NT, 256, 256, 2, 196 * 2);
    // 10. LN2 -> actbf (bf16)
    hipLaunchKernelGGL(ln_kernel, dim3(NT / 4), dim3(256), 0, stream,
                       out, ln2_g, ln2_b, dptr, actbf);
    // 11. fc1 + gelu -> hidden (bf16)
    hipLaunchKernelGGL(gemm_mfma<2>, dim3(196 * 8), dim3(256), 0, stream,
                       actbf, w1t, fc1_b, nullptr, (void*)hidden, NT, 1024, 256, 8, 196 * 8);
    // 12. fc2 + bias + residual(d_out) -> d_out f32
    hipLaunchKernelGGL(gemm_mfma<3>, dim3(196 * 2), dim3(256), 0, stream,
                       hidden, w2t, fc2_b, out, (void*)out, NT, 256, 1024, 2, 196 * 2);
}

// Round 8
// 386.438 us; speedup vs baseline: 1.1361x; 1.0262x over previous
//
#include <hip/hip_runtime.h>
#include <hip/hip_bf16.h>
#include <math.h>

// Problem constants (fixed by setup_inputs)
#define BB 8
#define HH 56
#define WW 56
#define NN (HH*WW)          // 3136
#define CC 256
#define NH 8
#define NT (BB*NN)          // 25088
#define HID 128
#define MH 1024
#define SCALE 0.17677669529663687f   // 32^-0.5

typedef __attribute__((ext_vector_type(8))) short bf16x8;
typedef __attribute__((ext_vector_type(4))) float f32x4;

__device__ __forceinline__ ushort f2bf(float f) {
    __hip_bfloat16 h = __float2bfloat16(f);
    return *(ushort*)&h;
}
__device__ __forceinline__ float bf2f(ushort u) {
    union { unsigned int i; float f; } x; x.i = ((unsigned int)u) << 16; return x.f;
}
__device__ __forceinline__ uint pk2(float lo, float hi) {
    return ((uint)f2bf(hi) << 16) | (uint)f2bf(lo);
}
__device__ __forceinline__ float unlo(uint u) { return __uint_as_float(u << 16); }
__device__ __forceinline__ float unhi(uint u) { return __uint_as_float(u & 0xFFFF0000u); }

__device__ __forceinline__ void gload16(const void* g, void* s) {
    __builtin_amdgcn_global_load_lds(
        (const __attribute__((address_space(1))) void*)g,
        (__attribute__((address_space(3))) void*)s, 16, 0, 0);
}

// ---------------- weight transpose + f32->bf16 + epilogue permutation ------
// w[K][N] -> wt[perm(N)][K]; within each 64-col block, permuted position
// p = j*16+lrow holds original column 4*lrow+j, so MFMA lane lrow's 4
// j-fragments are 4 CONTIGUOUS output columns (vectorized C-store).
__global__ __launch_bounds__(256) void wtrans_kernel(
    const float* __restrict__ w, ushort* __restrict__ wt, int K, int N)
{
    __shared__ float tile[32][33];
    const int t = threadIdx.x;
    const int col = t & 31, rw = t >> 5;
    const int k0 = blockIdx.y * 32, n0 = blockIdx.x * 32;
    #pragma unroll
    for (int i = rw; i < 32; i += 8)
        tile[i][col] = w[(size_t)(k0 + i) * N + n0 + col];
    __syncthreads();
    #pragma unroll
    for (int i = rw; i < 32; i += 8) {
        int n = n0 + i;
        int nl = n & 63;
        int np = (n & ~63) | ((nl & 3) * 16 + (nl >> 2));
        wt[(size_t)np * K + k0 + col] = f2bf(tile[col][i]);
    }
}

// ---------------- pack CRPE weights: [qq][49][32] bf16-pairs ----------------
__global__ __launch_bounds__(256) void wpack_kernel(
    const float* __restrict__ w3, const float* __restrict__ b3,
    const float* __restrict__ w5, const float* __restrict__ b5,
    const float* __restrict__ w7, const float* __restrict__ b7,
    uint* __restrict__ wt, float* __restrict__ bt)
{
    const int qq = blockIdx.x;
    const int KSQ = (qq == 0) ? 3 : (qq == 1) ? 5 : 7;
    for (int idx = threadIdx.x; idx < 49 * 32; idx += 256) {
        int tap = idx >> 5, p = idx & 31;
        int cA = qq * 64 + 2 * p;
        float lo = 0.f, hi = 0.f;
        if (tap < KSQ * KSQ) {
            int dy = tap / KSQ, dx = tap - dy * KSQ;
            const float* wb; int kslo;
            if (cA < 64)       { wb = w3 + cA * 9;          kslo = 3; }
            else if (cA < 160) { wb = w5 + (cA - 64) * 25;  kslo = 5; }
            else               { wb = w7 + (cA - 160) * 49; kslo = 7; }
            int offp = KSQ / 2 - kslo / 2;
            int sy = dy - offp, sx = dx - offp;
            if (sy >= 0 && sy < kslo && sx >= 0 && sx < kslo) {
                lo = wb[sy * kslo + sx];
                hi = wb[kslo * kslo + sy * kslo + sx];
            }
        }
        wt[(qq * 49 + tap) * 32 + p] = pk2(lo, hi);
    }
    if (threadIdx.x < 32) {
        int p = threadIdx.x, cA = qq * 64 + 2 * p;
        float blo, bhi;
        if (cA < 64)       { blo = b3[cA];       bhi = b3[cA + 1]; }
        else if (cA < 160) { blo = b5[cA - 64];  bhi = b5[cA - 63]; }
        else               { blo = b7[cA - 160]; bhi = b7[cA - 159]; }
        bt[(qq * 32 + p) * 2]     = blo;
        bt[(qq * 32 + p) * 2 + 1] = bhi;
    }
}

// ---------------- pack CPE weights: [qq][9][32] bf16-pairs ----------------
__global__ __launch_bounds__(256) void cpack_kernel(
    const float* __restrict__ w, const float* __restrict__ bias,
    uint* __restrict__ wt, float* __restrict__ bt)
{
    const int qq = blockIdx.x;
    for (int idx = threadIdx.x; idx < 9 * 32; idx += 256) {
        int tap = idx >> 5, p = idx & 31;
        int cA = qq * 64 + 2 * p;
        wt[(qq * 9 + tap) * 32 + p] = pk2(w[cA * 9 + tap], w[(cA + 1) * 9 + tap]);
    }
    if (threadIdx.x < 32) {
        int p = threadIdx.x, cA = qq * 64 + 2 * p;
        bt[(qq * 32 + p) * 2]     = bias[cA];
        bt[(qq * 32 + p) * 2 + 1] = bias[cA + 1];
    }
}

// ---------------- CPE: depthwise 3x3 + bias + residual (sliding window) ----
__global__ __launch_bounds__(256) void cpe_kernel(
    const float* __restrict__ x, const uint* __restrict__ wtab,
    const float* __restrict__ btab, float* __restrict__ out)
{
    __shared__ uint vt[4 * 34 * 32];
    const int qq = blockIdx.x >> 1, hx = blockIdx.x & 1;
    const int y0 = blockIdx.y * 2, b = blockIdx.z;
    const int x0 = hx * 28;
    const int t = threadIdx.x;
    const int c0 = qq * 64;
    const int p = t & 31;

    uint wpk[9];
    #pragma unroll
    for (int i = 0; i < 9; ++i) wpk[i] = wtab[(qq * 9 + i) * 32 + p];
    const float2 bb = *(const float2*)(btab + (qq * 32 + p) * 2);

    for (int pos = t >> 5; pos < 4 * 34; pos += 8) {
        int row = pos / 34, col = pos - row * 34;
        int gy = y0 + row - 1, gx = x0 + col - 3;
        float2 v = {0.f, 0.f};
        if ((unsigned)gy < 56u && (unsigned)gx < 56u)
            v = *(const float2*)(x + ((size_t)b * NN + gy * 56 + gx) * CC + c0 + 2 * p);
        vt[pos * 32 + p] = pk2(v.x, v.y);
    }
    __syncthreads();

    const int rseg = t >> 5;
    const int r = rseg >> 2, sg = rseg & 3;
    float accA[7], accB[7];
    #pragma unroll
    for (int k = 0; k < 7; ++k) { accA[k] = bb.x; accB[k] = bb.y; }

    #pragma unroll
    for (int dy = 0; dy < 3; ++dy) {
        const int rowbase = (r + dy) * 34 * 32;
        float fA[9], fB[9];
        #pragma unroll
        for (int u = 0; u < 9; ++u) {
            uint vv = vt[rowbase + (sg * 7 + 2 + u) * 32 + p];
            fA[u] = unlo(vv); fB[u] = unhi(vv);
        }
        #pragma unroll
        for (int dx = 0; dx < 3; ++dx) {
            uint wv = wpk[dy * 3 + dx];
            float wl = unlo(wv), wh = unhi(wv);
            #pragma unroll
            for (int k = 0; k < 7; ++k) {
                accA[k] = fmaf(fA[dx + k], wl, accA[k]);
                accB[k] = fmaf(fB[dx + k], wh, accB[k]);
            }
        }
    }

    const int cA = c0 + 2 * p;
    const int ytok = y0 + r;
    #pragma unroll
    for (int k = 0; k < 7; ++k) {
        size_t tok = (size_t)b * NN + ytok * 56 + x0 + sg * 7 + k;
        float2 res = *(const float2*)(x + tok * CC + cA);
        float2 o = { accA[k] + res.x, accB[k] + res.y };
        *(float2*)(out + tok * CC + cA) = o;
    }
}

// ---------------- LayerNorm over C=256, wave-per-row, bf16 out ----------------
__global__ __launch_bounds__(256) void ln_kernel(
    const float* __restrict__ src, const float* __restrict__ g_all,
    const float* __restrict__ b_all, const int* __restrict__ dptr,
    ushort* __restrict__ dst)
{
    const int wid = threadIdx.x >> 6, lane = threadIdx.x & 63;
    const int row = blockIdx.x * 4 + wid;
    const int d = *dptr;
    const float* g = g_all + d * CC;
    const float* be = b_all + d * CC;
    const float* p = src + (size_t)row * CC;
    float4 v = *(const float4*)(p + lane * 4);
    float s = v.x + v.y + v.z + v.w;
    float sq = v.x*v.x + v.y*v.y + v.z*v.z + v.w*v.w;
    #pragma unroll
    for (int off = 1; off < 64; off <<= 1) {
        s  += __shfl_xor(s, off);
        sq += __shfl_xor(sq, off);
    }
    const float mean = s * (1.f / CC);
    const float var = sq * (1.f / CC) - mean * mean;
    const float rs = rsqrtf(var + 1e-5f);
    float4 g4 = *(const float4*)(g + lane * 4);
    float4 b4 = *(const float4*)(be + lane * 4);
    ushort4 o4;
    o4.x = f2bf((v.x - mean) * rs * g4.x + b4.x);
    o4.y = f2bf((v.y - mean) * rs * g4.y + b4.y);
    o4.z = f2bf((v.z - mean) * rs * g4.z + b4.z);
    o4.w = f2bf((v.w - mean) * rs * g4.w + b4.w);
    *(ushort4*)(dst + (size_t)row * CC + lane * 4) = o4;
}

// ---------------- bf16 MFMA GEMM: C = A[M][K] @ Bt_perm[N][K]^T ----------------
// EPI: 1 = bf16 raw, 2 = bf16 bias+gelu, 3 = f32 bias+residual
// 2-phase pipelined (T3-minimum): double-buffered LDS, stage(next) issued
// BEFORE compute(cur), vmcnt(0) drained AFTER compute, one raw barrier/tile.
template<int EPI>
__global__ __launch_bounds__(256) void gemm_mfma(
    const ushort* __restrict__ A, const ushort* __restrict__ Bt,
    const float* __restrict__ bias, const float* __restrict__ res,
    void* __restrict__ Cv, int M, int N, int K, int nbn, int nwg)
{
    __shared__ __align__(16) ushort Als[2][128 * 32];
    __shared__ __align__(16) ushort Bls[2][128 * 32];
    const int t = threadIdx.x;
    // m204 bijective XCD swizzle
    const int lin = blockIdx.x;
    const int q8 = nwg >> 3, r8 = nwg & 7;
    const int xcd = lin & 7, i8 = lin >> 3;
    const int wgid = (xcd < r8 ? xcd * (q8 + 1) : r8 * (q8 + 1) + (xcd - r8) * q8) + i8;
    const int bm = wgid / nbn, bn = wgid - bm * nbn;
    const int brow = bm * 128, bcol = bn * 128;
    const int lane = t & 63, w = t >> 6;
    const int wr = w >> 1, wc = w & 1;
    const int lrow = lane & 15, lko = (lane >> 4) * 8;

    const ushort* gA0 = A + (size_t)(brow + (t >> 2)) * K + (t & 3) * 8;
    const ushort* gA1 = gA0 + (size_t)64 * K;
    const ushort* gB0 = Bt + (size_t)(bcol + (t >> 2)) * K + (t & 3) * 8;
    const ushort* gB1 = gB0 + (size_t)64 * K;
    const int dOff = t * 8;   // ushort offset of this thread's 16B staging slot

    f32x4 acc[4][4] = {};

    // prologue: stage tile 0 into buffer 0, drain, barrier
    gload16(gA0, &Als[0][dOff]);
    gload16(gA1, &Als[0][64 * 32 + dOff]);
    gload16(gB0, &Bls[0][dOff]);
    gload16(gB1, &Bls[0][64 * 32 + dOff]);
    asm volatile("s_waitcnt vmcnt(0)" ::: "memory");
    __builtin_amdgcn_s_barrier();

    const int KT = K >> 5;
    int cur = 0;
    for (int it = 0; it < KT; ++it) {
        if (it + 1 < KT) {
            const int ktn = (it + 1) << 5;
            gload16(gA0 + ktn, &Als[cur ^ 1][dOff]);
            gload16(gA1 + ktn, &Als[cur ^ 1][64 * 32 + dOff]);
            gload16(gB0 + ktn, &Bls[cur ^ 1][dOff]);
            gload16(gB1 + ktn, &Bls[cur ^ 1][64 * 32 + dOff]);
        }
        // compute from buf[cur] while next tile's loads are in flight
        bf16x8 af[4], bfr[4];
        #pragma unroll
        for (int i = 0; i < 4; ++i)
            af[i] = *(const bf16x8*)&Als[cur][(wr * 64 + i * 16 + lrow) * 32 + lko];
        #pragma unroll
        for (int j = 0; j < 4; ++j)
            bfr[j] = *(const bf16x8*)&Bls[cur][(wc * 64 + j * 16 + lrow) * 32 + lko];
        #pragma unroll
        for (int i = 0; i < 4; ++i)
            #pragma unroll
            for (int j = 0; j < 4; ++j)
                acc[i][j] = __builtin_amdgcn_mfma_f32_16x16x32_bf16(
                    af[i], bfr[j], acc[i][j], 0, 0, 0);
        // drain next-tile staging (latency was hidden under compute), sync
        asm volatile("s_waitcnt vmcnt(0)" ::: "memory");
        __builtin_amdgcn_s_barrier();
        cur ^= 1;
    }

    float* Cf = (float*)Cv;
    ushort* Ch = (ushort*)Cv;
    const int col0 = bcol + wc * 64 + 4 * lrow;   // 4 contiguous original cols
    float bias4[4] = {0.f, 0.f, 0.f, 0.f};
    if (EPI >= 2) {
        float4 bv = *(const float4*)(bias + col0);
        bias4[0] = bv.x; bias4[1] = bv.y; bias4[2] = bv.z; bias4[3] = bv.w;
    }
    #pragma unroll
    for (int i = 0; i < 4; ++i) {
        #pragma unroll
        for (int r = 0; r < 4; ++r) {
            const int row = brow + wr * 64 + i * 16 + (lane >> 4) * 4 + r;
            size_t off = (size_t)row * N + col0;
            float o[4];
            #pragma unroll
            for (int j = 0; j < 4; ++j) o[j] = acc[i][j][r] + bias4[j];
            if (EPI == 2) {
                #pragma unroll
                for (int j = 0; j < 4; ++j)
                    o[j] = 0.5f * o[j] * (1.f + erff(o[j] * 0.70710678118654752f));
                ushort4 st = { f2bf(o[0]), f2bf(o[1]), f2bf(o[2]), f2bf(o[3]) };
                *(ushort4*)(Ch + off) = st;
            } else if (EPI == 1) {
                ushort4 st = { f2bf(o[0]), f2bf(o[1]), f2bf(o[2]), f2bf(o[3]) };
                *(ushort4*)(Ch + off) = st;
            } else {
                float4 rv = *(const float4*)(res + off);
                float4 st = { o[0] + rv.x, o[1] + rv.y, o[2] + rv.z, o[3] + rv.w };
                *(float4*)(Cf + off) = st;
            }
        }
    }
}

// ---------------- k softmax: per-chunk column max + reduce (bf16 qkv) -------
__global__ __launch_bounds__(256) void kmax1_kernel(
    const ushort* __restrict__ qkv, float* __restrict__ pmax)
{
    const int chunk = blockIdx.x, b = blockIdx.y, c = threadIdx.x;
    const ushort* kb = qkv + (size_t)(b * NN + chunk * 98) * 768 + 256 + c;
    float m = -3.4e38f;
    for (int i = 0; i < 98; ++i) m = fmaxf(m, bf2f(kb[(size_t)i * 768]));
    pmax[(b * 32 + chunk) * CC + c] = m;
}

__global__ __launch_bounds__(256) void kmax2_kernel(
    const float* __restrict__ pmax, float* __restrict__ cmax)
{
    const int b = blockIdx.x, c = threadIdx.x;
    float m = -3.4e38f;
    #pragma unroll
    for (int i = 0; i < 32; ++i) m = fmaxf(m, pmax[(b * 32 + i) * CC + c]);
    cmax[b * CC + c] = m;
}

// ---------------- kv partial: per-chunk exp-weighted sums (bf16 qkv) --------
__global__ __launch_bounds__(256) void kvacc_kernel(
    const ushort* __restrict__ qkv, const float* __restrict__ cmax,
    float* __restrict__ partial, float* __restrict__ psum)
{
    const int chunk = blockIdx.x, h = blockIdx.y, b = blockIdx.z;
    const int t = threadIdx.x;
    const int ck = t & 31, g = t >> 5;
    const int n0 = chunk * 196;
    const ushort* kb = qkv + (size_t)(b * NN + n0) * 768 + 256 + h * 32 + ck;
    const ushort* vb = qkv + (size_t)(b * NN + n0) * 768 + 512 + h * 32 + g * 4;
    const float cm = cmax[b * CC + h * 32 + ck];
    float a0 = 0.f, a1 = 0.f, a2 = 0.f, a3 = 0.f, s = 0.f;
    for (int i = 0; i < 196; ++i) {
        float e = __expf(bf2f(kb[(size_t)i * 768]) - cm);
        ushort4 v4 = *(const ushort4*)(vb + (size_t)i * 768);
        a0 += e * bf2f(v4.x); a1 += e * bf2f(v4.y);
        a2 += e * bf2f(v4.z); a3 += e * bf2f(v4.w);
        s += e;
    }
    float4 o = {a0, a1, a2, a3};
    *(float4*)(partial + ((((size_t)chunk * 8 + b) * 8 + h) * 32 + ck) * 32 + g * 4) = o;
    if (g == 0) psum[((chunk * 8 + b) * 8 + h) * 32 + ck] = s;
}

__global__ __launch_bounds__(256) void kvnorm_kernel(
    const float* __restrict__ partial, const float* __restrict__ psum,
    float* __restrict__ kv)
{
    const int idx = blockIdx.x * 256 + threadIdx.x;   // [b][h][ck][cv]
    const int ckidx = idx >> 5;
    float sum = 0.f, cs = 0.f;
    #pragma unroll
    for (int ch = 0; ch < 16; ++ch) {
        sum += partial[(size_t)ch * 65536 + idx];
        cs  += psum[ch * 2048 + ckidx];
    }
    kv[idx] = sum / cs;
}

// ---------------- fa GEMM: fa[b,h] = q[b,:,h] @ kv[b,h]  (into k-slot) ------
__global__ __launch_bounds__(256) void fa_kernel(
    ushort* __restrict__ qkv, const float* __restrict__ kvb)
{
    const int mt = blockIdx.x, h = blockIdx.y, b = blockIdx.z;
    const int t = threadIdx.x;
    const int lane = t & 63, wv = t >> 6;
    const int row0 = mt * 448 + wv * 112;
    const int lr = lane & 15, lk = (lane >> 4) * 8;

    bf16x8 bfr[2];
    #pragma unroll
    for (int jj = 0; jj < 2; ++jj)
        #pragma unroll
        for (int e = 0; e < 8; ++e)
            bfr[jj][e] = (short)f2bf(kvb[((size_t)(b * 8 + h) * 32 + lk + e) * 32 + 2 * lr + jj]);

    #pragma unroll
    for (int i = 0; i < 7; ++i) {
        size_t tok = (size_t)b * NN + row0 + i * 16 + lr;
        bf16x8 af = *(const bf16x8*)(qkv + tok * 768 + h * 32 + lk);
        f32x4 a0 = {0.f, 0.f, 0.f, 0.f}, a1 = {0.f, 0.f, 0.f, 0.f};
        a0 = __builtin_amdgcn_mfma_f32_16x16x32_bf16(af, bfr[0], a0, 0, 0, 0);
        a1 = __builtin_amdgcn_mfma_f32_16x16x32_bf16(af, bfr[1], a1, 0, 0, 0);
        #pragma unroll
        for (int r = 0; r < 4; ++r) {
            size_t trow = (size_t)b * NN + row0 + i * 16 + (lane >> 4) * 4 + r;
            *(uint*)(qkv + trow * 768 + 256 + h * 32 + 2 * lr) = pk2(a0[r], a1[r]);
        }
    }
}

// ---------------- domain gating ----------------
__global__ __launch_bounds__(256) void da_kernel(
    const float* __restrict__ dl, const float* __restrict__ w1,
    const float* __restrict__ b1, const float* __restrict__ w2,
    const float* __restrict__ b2, float* __restrict__ da)
{
    const int b = blockIdx.x, t = threadIdx.x;
    __shared__ float r[HID];
    __shared__ float raw[CC];
    if (t < HID) {
        float s = b1[t];
        #pragma unroll
        for (int k = 0; k < 4; ++k) s += dl[b * 4 + k] * w1[k * HID + t];
        r[t] = fmaxf(s, 0.f);
    }
    __syncthreads();
    float s = b2[t];
    for (int j = 0; j < HID; ++j) s += r[j] * w2[j * CC + t];
    raw[t] = s;
    __syncthreads();
    const int ch = t & 31;
    float m = -3.4e38f;
    #pragma unroll
    for (int hh = 0; hh < NH; ++hh) m = fmaxf(m, raw[hh * 32 + ch]);
    float ssum = 0.f;
    #pragma unroll
    for (int hh = 0; hh < NH; ++hh) ssum += __expf(raw[hh * 32 + ch] - m);
    da[b * CC + t] = __expf(raw[t] - m) / ssum;
}

// ---------------- combine: conv + fa + gating (sliding window, bf16 qkv) ----
template<int KS>
__device__ __forceinline__ void comb_body(
    uint* vt, int qq,
    const ushort* __restrict__ qkv, const float* __restrict__ da,
    const uint* __restrict__ wtab, const float* __restrict__ btab,
    ushort* __restrict__ out)
{
    constexpr int R = KS / 2;
    constexpr int TR = KS + 1;
    constexpr int WCOLS = 7 + 2 * R;
    const int hx = blockIdx.x & 1;
    const int y0 = blockIdx.y * 2, b = blockIdx.z;
    const int x0 = hx * 28;
    const int t = threadIdx.x;
    const int c0 = qq * 64;
    const int p = t & 31;

    uint wpk[KS * KS];
    #pragma unroll
    for (int i = 0; i < KS * KS; ++i) wpk[i] = wtab[(qq * 49 + i) * 32 + p];
    const float2 bb = *(const float2*)(btab + (qq * 32 + p) * 2);

    // stage: direct uint (bf16-pair) copy from global, bank = p
    for (int pos = t >> 5; pos < TR * 34; pos += 8) {
        int row = pos / 34, col = pos - row * 34;
        int gy = y0 + row - R, gx = x0 + col - 3;
        uint v = 0;
        if ((unsigned)gy < 56u && (unsigned)gx < 56u)
            v = *(const uint*)(qkv + ((size_t)b * NN + gy * 56 + gx) * 768 + 512 + c0 + 2 * p);
        vt[pos * 32 + p] = v;
    }
    __syncthreads();

    const int rseg = t >> 5;
    const int r = rseg >> 2, sg = rseg & 3;
    float accA[7], accB[7];
    #pragma unroll
    for (int k = 0; k < 7; ++k) { accA[k] = bb.x; accB[k] = bb.y; }

    #pragma unroll
    for (int dy = 0; dy < KS; ++dy) {
        const int rowbase = (r + dy) * 34 * 32;
        float fA[WCOLS], fB[WCOLS];
        #pragma unroll
        for (int u = 0; u < WCOLS; ++u) {
            uint vv = vt[rowbase + (sg * 7 + 3 - R + u) * 32 + p];
            fA[u] = unlo(vv); fB[u] = unhi(vv);
        }
        #pragma unroll
        for (int dx = 0; dx < KS; ++dx) {
            uint wv = wpk[dy * KS + dx];
            float wl = unlo(wv), wh = unhi(wv);
            #pragma unroll
            for (int k = 0; k < 7; ++k) {
                accA[k] = fmaf(fA[dx + k], wl, accA[k]);
                accB[k] = fmaf(fB[dx + k], wh, accB[k]);
            }
        }
    }

    const int cA = c0 + 2 * p;
    const float2 da2 = *(const float2*)(da + b * CC + cA);
    const int ytok = y0 + r;
    #pragma unroll
    for (int k = 0; k < 7; ++k) {
        size_t tok = (size_t)b * NN + ytok * 56 + x0 + sg * 7 + k;
        uint qw = *(const uint*)(qkv + tok * 768 + cA);
        uint fw = *(const uint*)(qkv + tok * 768 + 256 + cA);
        ushort2 o = { f2bf(da2.x * (SCALE * unlo(fw) + unlo(qw) * accA[k])),
                      f2bf(da2.y * (SCALE * unhi(fw) + unhi(qw) * accB[k])) };
        *(ushort2*)(out + tok * CC + cA) = o;
    }
}

__global__ __launch_bounds__(256) void combine_kernel(
    const ushort* __restrict__ qkv, const float* __restrict__ da,
    const uint* __restrict__ wtab, const float* __restrict__ btab,
    ushort* __restrict__ out)
{
    __shared__ uint vt[8 * 34 * 32];
    switch (blockIdx.x >> 1) {
    case 0:  comb_body<3>(vt, 0, qkv, da, wtab, btab, out); break;
    case 1:  comb_body<5>(vt, 1, qkv, da, wtab, btab, out); break;
    case 2:  comb_body<7>(vt, 2, qkv, da, wtab, btab, out); break;
    default: comb_body<7>(vt, 3, qkv, da, wtab, btab, out); break;
    }
}

// ---------------- launch ----------------
extern "C" void kernel_launch(void* const* d_in, const int* in_sizes, int n_in,
                              void* d_out, int out_size, void* d_ws, size_t ws_size,
                              hipStream_t stream)
{
    const float* x       = (const float*)d_in[0];
    const float* dlab    = (const float*)d_in[1];
    const float* cpe_w   = (const float*)d_in[2];
    const float* cpe_b   = (const float*)d_in[3];
    const float* ln1_g   = (const float*)d_in[4];
    const float* ln1_b   = (const float*)d_in[5];
    const float* qkv_w   = (const float*)d_in[6];
    const float* proj_w  = (const float*)d_in[7];
    const float* proj_b  = (const float*)d_in[8];
    const float* dl_w1   = (const float*)d_in[9];
    const float* dl_b1   = (const float*)d_in[10];
    const float* dl_w2   = (const float*)d_in[11];
    const float* dl_b2   = (const float*)d_in[12];
    const float* crpe_w3 = (const float*)d_in[13];
    const float* crpe_b3 = (const float*)d_in[14];
    const float* crpe_w5 = (const float*)d_in[15];
    const float* crpe_b5 = (const float*)d_in[16];
    const float* crpe_w7 = (const float*)d_in[17];
    const float* crpe_b7 = (const float*)d_in[18];
    const float* ln2_g   = (const float*)d_in[19];
    const float* ln2_b   = (const float*)d_in[20];
    const float* fc1_w   = (const float*)d_in[21];
    const float* fc1_b   = (const float*)d_in[22];
    const float* fc2_w   = (const float*)d_in[23];
    const float* fc2_b   = (const float*)d_in[24];
    const int*   dptr    = (const int*)d_in[27];

    float* out = (float*)d_out;
    char* W = (char*)d_ws;
    size_t off = 0;
    float* x1 = (float*)(W + off);          off += (size_t)NT * CC * 4;    // f32 [NT,C]
    // union region: qkv bf16 [NT,768] (38.6MB) / mlp hidden bf16 [NT,1024] (51.4MB)
    ushort* qkvb = (ushort*)(W + off);
    ushort* hidden = (ushort*)(W + off);    off += (size_t)NT * MH * 2;
    ushort* actbf = (ushort*)(W + off);     off += (size_t)NT * CC * 2;    // bf16 [NT,C]
    // overlay: kv partials live only between qkv-GEMM and fa, while actbf is dead
    float* partial = (float*)actbf;                    // 16*65536 f32 = 4 MB
    float* psum = partial + (size_t)16 * 65536;        // 32768 f32
    float* kvb = (float*)(W + off);         off += (size_t)65536 * 4;
    float* dab = (float*)(W + off);         off += (size_t)BB * CC * 4;
    float* pmax = (float*)(W + off);        off += (size_t)BB * 32 * CC * 4;
    float* cmax = (float*)(W + off);        off += (size_t)BB * CC * 4;
    ushort* wq  = (ushort*)(W + off);       off += (size_t)768 * 256 * 2;
    ushort* wp  = (ushort*)(W + off);       off += (size_t)256 * 256 * 2;
    ushort* w1t = (ushort*)(W + off);       off += (size_t)1024 * 256 * 2;
    ushort* w2t = (ushort*)(W + off);       off += (size_t)256 * 1024 * 2;
    uint* wcomb = (uint*)(W + off);         off += (size_t)4 * 49 * 32 * 4;
    float* bcomb = (float*)(W + off);       off += (size_t)4 * 32 * 2 * 4;
    uint* wcpe = (uint*)(W + off);          off += (size_t)4 * 9 * 32 * 4;
    float* bcpe = (float*)(W + off);        off += (size_t)4 * 32 * 2 * 4;

    // 0. weight packing / transpose (tiny, one-time per launch)
    hipLaunchKernelGGL(wpack_kernel, dim3(4), dim3(256), 0, stream,
                       crpe_w3, crpe_b3, crpe_w5, crpe_b5, crpe_w7, crpe_b7, wcomb, bcomb);
    hipLaunchKernelGGL(cpack_kernel, dim3(4), dim3(256), 0, stream, cpe_w, cpe_b, wcpe, bcpe);
    hipLaunchKernelGGL(wtrans_kernel, dim3(768 / 32, 256 / 32), dim3(256), 0, stream, qkv_w, wq, 256, 768);
    hipLaunchKernelGGL(wtrans_kernel, dim3(256 / 32, 256 / 32), dim3(256), 0, stream, proj_w, wp, 256, 256);
    hipLaunchKernelGGL(wtrans_kernel, dim3(1024 / 32, 256 / 32), dim3(256), 0, stream, fc1_w, w1t, 256, 1024);
    hipLaunchKernelGGL(wtrans_kernel, dim3(256 / 32, 1024 / 32), dim3(256), 0, stream, fc2_w, w2t, 1024, 256);
    // 1. CPE -> x1 (f32)
    hipLaunchKernelGGL(cpe_kernel, dim3(8, 28, 8), dim3(256), 0, stream, x, wcpe, bcpe, x1);
    // 2. domain gating
    hipLaunchKernelGGL(da_kernel, dim3(BB), dim3(256), 0, stream,
                       dlab, dl_w1, dl_b1, dl_w2, dl_b2, dab);
    // 3. LN1 -> actbf (bf16)
    hipLaunchKernelGGL(ln_kernel, dim3(NT / 4), dim3(256), 0, stream,
                       x1, ln1_g, ln1_b, dptr, actbf);
    // 4. qkv GEMM: [NT,256]bf16 @ [768,256]^T -> qkvb bf16
    hipLaunchKernelGGL(gemm_mfma<1>, dim3(196 * 6), dim3(256), 0, stream,
                       actbf, wq, nullptr, nullptr, (void*)qkvb, NT, 768, 256, 6, 196 * 6);
    // 5. k column max (chunked) + reduce
    hipLaunchKernelGGL(kmax1_kernel, dim3(32, 8), dim3(256), 0, stream, qkvb, pmax);
    hipLaunchKernelGGL(kmax2_kernel, dim3(8), dim3(256), 0, stream, pmax, cmax);
    // 6. kv partial sums + normalize
    hipLaunchKernelGGL(kvacc_kernel, dim3(16, 8, 8), dim3(256), 0, stream,
                       qkvb, cmax, partial, psum);
    hipLaunchKernelGGL(kvnorm_kernel, dim3(256), dim3(256), 0, stream,
                       partial, psum, kvb);
    // 7. fa = q @ kv -> written into qkvb's k-slot (k is dead now)
    hipLaunchKernelGGL(fa_kernel, dim3(7, 8, 8), dim3(256), 0, stream, qkvb, kvb);
    // 8. combine (conv + fa + gating) -> actbf (bf16)
    hipLaunchKernelGGL(combine_kernel, dim3(8, 28, 8), dim3(256), 0, stream,
                       qkvb, dab, wcomb, bcomb, actbf);
    // 9. proj GEMM + bias + residual(x1) -> d_out f32
    hipLaunchKernelGGL(gemm_mfma<3>, dim3(196 * 2), dim3(256), 0, stream,
                       actbf, wp, proj_b, x1, (void*)out, NT, 256, 256, 2, 196 * 2);
    // 10. LN2 -> actbf (bf16)
    hipLaunchKernelGGL(ln_kernel, dim3(NT / 4), dim3(256), 0, stream,
                       out, ln2_g, ln2_b, dptr, actbf);
    // 11. fc1 + gelu -> hidden (bf16)
    hipLaunchKernelGGL(gemm_mfma<2>, dim3(196 * 8), dim3(256), 0, stream,
                       actbf, w1t, fc1_b, nullptr, (void*)hidden, NT, 1024, 256, 8, 196 * 8);
    // 12. fc2 + bias + residual(d_out) -> d_out f32
    hipLaunchKernelGGL(gemm_mfma<3>, dim3(196 * 2), dim3(256), 0, stream,
                       hidden, w2t, fc2_b, out, (void*)out, NT, 256, 1024, 2, 196 * 2);
}